// Round 11
// baseline (212.242 us; speedup 1.0000x reference)
//
#include <hip/hip_runtime.h>

#define N_NODES 50000
#define N_EDGES 800000
#define D 128
#define BN_EPS 1e-5f
#define AGG_BLOCKS 2048
#define CHUNKS 64
#define EPC (N_EDGES / CHUNKS)    // 12500 edges per chunk (u16-safe ranks)
#define EPC4 (EPC / 4)            // 3125 int4 loads (chunk base 16B-aligned)
#define QUART_BINS 12800          // node-range quarter
#define QUART_U32 6400            // u32 words per quarter (2 bins/word)
#define NB_MERGE 100              // merge blocks: 512 consecutive nodes each
#define NB_PER_Q 25               // merge blocks per quarter (25*256 = 6400 words)
#define GEMM_BLKS 782             // ceil(50000/64)
#define FILL_BLKS 256             // 64 chunks x 4 quarters

typedef short bf16x8 __attribute__((ext_vector_type(8)));
typedef float f32x4  __attribute__((ext_vector_type(4)));
typedef float f32x2  __attribute__((ext_vector_type(2)));
typedef unsigned int u32x4 __attribute__((ext_vector_type(4)));
typedef int i32x4 __attribute__((ext_vector_type(4)));   // native vec: nontemporal-safe

// ---------------- workspace layout (bytes) ----------------
// cnt_in @0 (256KB)  cnt_out @262144 (256KB)  row_ptr @524288 (local prefix)
// scsh @1310720  blk_sum @1312768 (100 ints)  csr_src @1576960 (3.2MB)
// hwb8(fp8 [row][col]) @4800000 (6.4MB)  resb(bf16) @11200000 (12.8MB)
// yb @24000000 (12.8MB)  parts @36800000 (2.1MB)
// pW @38897152  pWr @38929920  histD @38962688 (6.55MB)  histS @45516288 (6.55MB)
// hist layout: [(quarter*CHUNKS + chunk)][QUART_U32]

__device__ __forceinline__ unsigned int pack_rne(float a, float b) {
    unsigned int ua = __float_as_uint(a); ua += 0x7fffu + ((ua >> 16) & 1u);
    unsigned int ub = __float_as_uint(b); ub += 0x7fffu + ((ub >> 16) & 1u);
    return (ua >> 16) | (ub & 0xffff0000u);
}
__device__ __forceinline__ unsigned short pack1_rne(float a) {
    unsigned int ua = __float_as_uint(a); ua += 0x7fffu + ((ua >> 16) & 1u);
    return (unsigned short)(ua >> 16);
}
__device__ __forceinline__ unsigned char pack1_fp8(float a) {
    unsigned int u = __builtin_amdgcn_cvt_pk_fp8_f32(a, a, 0, false);
    return (unsigned char)(u & 0xffu);
}

// Shared: per-block LDS scan of the NB_MERGE block totals. sh[] = INCLUSIVE sums.
__device__ __forceinline__ void scan_blksum(const int* __restrict__ blk_sum,
                                            int* sh, int t) {
    int v = (t < NB_MERGE) ? blk_sum[t] : 0;
    if (t < 256) sh[t] = v;
    __syncthreads();
    int inc = v;
    #pragma unroll
    for (int off = 1; off < 256; off <<= 1) {
        int u = (t >= off && t < 256) ? sh[t - off] : 0;
        __syncthreads();
        inc += u;
        if (t < 256) sh[t] = inc;
        __syncthreads();
    }
}
#define BLK_OFF(sh, mb) ((mb) ? (sh)[(mb) - 1] : 0)

// Privatized LDS histogram, grid (chunk[+pack], r-QUARTER, key) = 512 working
// blocks (2/CU), 25.6KB LDS each. int4 edge loads.
// Blocks x >= CHUNKS (y==0,z==0) do the W/Wr pre-pack.
__global__ __launch_bounds__(256) void hist_kernel(
        const int* __restrict__ dst, const int* __restrict__ src,
        unsigned int* __restrict__ histD, unsigned int* __restrict__ histS,
        const float* __restrict__ W, const float* __restrict__ Wr,
        uint4* __restrict__ pW, uint4* __restrict__ pWr) {
    __shared__ unsigned int h[QUART_U32];
    int tid = threadIdx.x;
    int c = blockIdx.x, r = blockIdx.y;
    if (c >= CHUNKS) {
        if (r != 0 || blockIdx.z != 0) return;
        int t = (c - CHUNKS) * 256 + tid;
        const float* S = (t & 2048) ? Wr : W;
        uint4* Dst     = (t & 2048) ? pWr : pW;
        int e = t & 2047;
        int lane = e & 63, ks = (e >> 6) & 3, ct = e >> 8;
        int n  = ct * 16 + (lane & 15);
        int k0 = ks * 32 + (lane >> 4) * 8;
        float v[8];
        #pragma unroll
        for (int j = 0; j < 8; j++) v[j] = S[(k0 + j) * D + n];
        uint4 rr;
        rr.x = pack_rne(v[0], v[1]); rr.y = pack_rne(v[2], v[3]);
        rr.z = pack_rne(v[4], v[5]); rr.w = pack_rne(v[6], v[7]);
        Dst[e] = rr;
        return;
    }
    const int* keys = blockIdx.z ? src : dst;
    unsigned int* hist = blockIdx.z ? histS : histD;
    for (int j = tid; j < QUART_U32; j += 256) h[j] = 0u;
    __syncthreads();
    int lo = r * QUART_BINS;
    const i32x4* keys4 = (const i32x4*)(keys + c * EPC);   // 16B-aligned
    for (int i = tid; i < EPC4; i += 256) {
        i32x4 k = __builtin_nontemporal_load(keys4 + i);
        int b0 = k.x - lo, b1 = k.y - lo, b2 = k.z - lo, b3 = k.w - lo;
        if ((unsigned)b0 < (unsigned)QUART_BINS) atomicAdd(&h[b0 >> 1], 1u << ((b0 & 1) * 16));
        if ((unsigned)b1 < (unsigned)QUART_BINS) atomicAdd(&h[b1 >> 1], 1u << ((b1 & 1) * 16));
        if ((unsigned)b2 < (unsigned)QUART_BINS) atomicAdd(&h[b2 >> 1], 1u << ((b2 & 1) * 16));
        if ((unsigned)b3 < (unsigned)QUART_BINS) atomicAdd(&h[b3 >> 1], 1u << ((b3 & 1) * 16));
    }
    __syncthreads();
    unsigned int* out = hist + ((size_t)(r * CHUNKS + c)) * QUART_U32;
    for (int j = tid; j < QUART_U32; j += 256) out[j] = h[j];
}

// merge, grid (100, key): each block = 256 words = 512 consecutive nodes.
__global__ __launch_bounds__(256) void merge_kernel(
        unsigned int* __restrict__ histD, unsigned int* __restrict__ histS,
        int* __restrict__ cnt_in, int* __restrict__ cnt_out,
        int* __restrict__ row_ptr, int* __restrict__ blk_sum) {
    __shared__ int sh[256];
    int t = threadIdx.x;
    int bx = blockIdx.x;
    int r = bx / NB_PER_Q;
    int q = (bx % NB_PER_Q) * 256 + t;         // word index within quarter
    int n0 = bx * 512 + t * 2;                 // consecutive node id
    if (blockIdx.y) {
        size_t base = (size_t)r * CHUNKS * QUART_U32 + q;
        unsigned int vals[CHUNKS];
        #pragma unroll
        for (int c = 0; c < CHUNKS; c++)
            vals[c] = histS[base + (size_t)c * QUART_U32];   // independent loads
        unsigned int lo = 0, hi = 0;
        #pragma unroll
        for (int c = 0; c < CHUNKS; c++) {
            lo += vals[c] & 0xffffu; hi += vals[c] >> 16;
        }
        cnt_out[n0]     = (int)lo;
        cnt_out[n0 + 1] = (int)hi;
        return;                                // no barriers taken
    }
    size_t base = (size_t)r * CHUNKS * QUART_U32 + q;
    unsigned int vals[CHUNKS];
    #pragma unroll
    for (int c = 0; c < CHUNKS; c++)
        vals[c] = histD[base + (size_t)c * QUART_U32];   // independent loads
    unsigned int lo = 0, hi = 0;
    #pragma unroll
    for (int c = 0; c < CHUNKS; c++) {
        unsigned int v = vals[c];
        histD[base + (size_t)c * QUART_U32] = lo | (hi << 16);  // exclusive prefix
        lo += v & 0xffffu; hi += v >> 16;
    }
    cnt_in[n0]     = (int)lo;
    cnt_in[n0 + 1] = (int)hi;
    // fused intra-block scan over this block's 512 node counts
    int pair = (int)lo + (int)hi;
    sh[t] = pair;
    __syncthreads();
    int inc = pair;
    #pragma unroll
    for (int off = 1; off < 256; off <<= 1) {
        int u = (t >= off) ? sh[t - off] : 0;
        __syncthreads();
        inc += u; sh[t] = inc;
        __syncthreads();
    }
    int excl = inc - pair;
    row_ptr[n0]     = excl;                    // LOCAL prefix (block-relative)
    row_ptr[n0 + 1] = excl + (int)lo;
    if (t == 255) blk_sum[bx] = inc;           // block TOTAL (nodes bx*512..+511)
}

// FUSED gemm + CSR-fill, one dispatch (independent consumers of merge's
// outputs; complementary bottlenecks: MFMA/VALU vs latency). 256 threads.
// blocks < GEMM_BLKS: MFMA dual GEMM. blocks >= GEMM_BLKS: counting-sort fill.
// LDS unioned: gemm xs[64][136] (17.4KB) vs fill h[QUART_U32]+sho (26.6KB).
__global__ __launch_bounds__(256) void gemfill_kernel(
        const float* __restrict__ x, const uint4* __restrict__ pW,
        const uint4* __restrict__ pWr, const float* __restrict__ br,
        const unsigned int* __restrict__ cnt_out, unsigned char* __restrict__ hwb8,
        unsigned short* __restrict__ resb,
        const int* __restrict__ src, const int* __restrict__ dst,
        const int* __restrict__ row_ptr, const unsigned int* __restrict__ histP,
        const int* __restrict__ blk_sum, int* __restrict__ csr_src) {
    __shared__ char smem[QUART_U32 * 4 + 1024];   // 26.6KB union
    int tid = threadIdx.x;
    if (blockIdx.x >= GEMM_BLKS) {
        // ---- CSR fill (256 threads) ----
        unsigned int* h = (unsigned int*)smem;
        int* sho = (int*)(smem + QUART_U32 * 4);
        scan_blksum(blk_sum, sho, tid);
        int fb = blockIdx.x - GEMM_BLKS;
        int c = fb & 63, s = fb >> 6;          // chunk, quarter
        int base = c * EPC;
        for (int j = tid; j < QUART_U32; j += 256) h[j] = 0u;
        __syncthreads();
        int lo = s * QUART_BINS;
        const unsigned int* pre_c = histP + ((size_t)(s * CHUNKS + c)) * QUART_U32;
        for (int i = tid; i < EPC; i += 256) {
            int d = __builtin_nontemporal_load(dst + base + i);
            int b = d - lo;
            if ((unsigned)b < (unsigned)QUART_BINS) {
                int shft = (b & 1) * 16;
                unsigned int old = atomicAdd(&h[b >> 1], 1u << shft);
                unsigned int rank = (old >> shft) & 0xffffu;
                unsigned int pre = (pre_c[b >> 1] >> shft) & 0xffffu;
                int p = row_ptr[d] + BLK_OFF(sho, d >> 9) + (int)(pre + rank);
                csr_src[p] = __builtin_nontemporal_load(src + base + i);
            }
        }
        return;
    }
    // ---- GEMM ----
    unsigned short (*xs)[136] = (unsigned short(*)[136])smem;
    int wid = tid >> 6, lane = tid & 63;
    int quad = lane >> 4, l15 = lane & 15;
    int r0b = blockIdx.x * 64;
    const float4* xg = (const float4*)(x + (size_t)r0b * D);
    int maxidx = (N_NODES - r0b) * (D / 4);
    #pragma unroll
    for (int i = 0; i < 8; i++) {
        int idx = tid + 256 * i;
        float4 v = (idx < maxidx) ? xg[idx] : make_float4(0.f, 0.f, 0.f, 0.f);
        int row = idx >> 5, c0 = (idx & 31) * 4;
        *(unsigned int*)&xs[row][c0]     = pack_rne(v.x, v.y);
        *(unsigned int*)&xs[row][c0 + 2] = pack_rne(v.z, v.w);
    }
    __syncthreads();
    int wrow0 = wid * 16;
    bf16x8 A[4];
    #pragma unroll
    for (int ks = 0; ks < 4; ks++)
        A[ks] = *(const bf16x8*)&xs[wrow0 + l15][ks * 32 + quad * 8];
    f32x4 accW[8], accR[8];
    #pragma unroll
    for (int ct = 0; ct < 8; ct++) { accW[ct] = (f32x4)0.f; accR[ct] = (f32x4)0.f; }
    #pragma unroll
    for (int ct = 0; ct < 8; ct++) {
        #pragma unroll
        for (int ks = 0; ks < 4; ks++) {
            union { bf16x8 v; uint4 u; } Bw, Br2;
            Bw.u  = pW [(ct * 4 + ks) * 64 + lane];
            Br2.u = pWr[(ct * 4 + ks) * 64 + lane];
            accW[ct] = __builtin_amdgcn_mfma_f32_16x16x32_bf16(A[ks], Bw.v,  accW[ct], 0, 0, 0);
            accR[ct] = __builtin_amdgcn_mfma_f32_16x16x32_bf16(A[ks], Br2.v, accR[ct], 0, 0, 0);
        }
    }
    int r0 = r0b + wrow0;
    float ro[4]; int rowok[4];
    #pragma unroll
    for (int reg = 0; reg < 4; reg++) {
        int row = r0 + quad * 4 + reg;
        rowok[reg] = row < N_NODES;
        int cw = (int)cnt_out[rowok[reg] ? row : N_NODES - 1];
        ro[reg] = rsqrtf((float)(cw > 1 ? cw : 1));
    }
    #pragma unroll
    for (int ct = 0; ct < 8; ct++) {
        int c = ct * 16 + l15;
        float brv = br[c];
        #pragma unroll
        for (int reg = 0; reg < 4; reg++) {
            int row = r0 + quad * 4 + reg;
            if (rowok[reg]) {
                hwb8[(size_t)row * D + c] = pack1_fp8(accW[ct][reg] * ro[reg]);
                resb[(size_t)row * D + c] = pack1_rne(fmaxf(accR[ct][reg] + brv, 0.f));
            }
        }
    }
}

__device__ __forceinline__ float bf_lo(unsigned int v) { return __uint_as_float(v << 16); }
__device__ __forceinline__ float bf_hi(unsigned int v) { return __uint_as_float(v & 0xffff0000u); }

// 16-value fp8 accumulate from one uint4 (8 cvt + 8 pk-add)
__device__ __forceinline__ void acc16(f32x2* a, const uint4 v) {
    a[0] += __builtin_amdgcn_cvt_pk_f32_fp8(v.x, false);
    a[1] += __builtin_amdgcn_cvt_pk_f32_fp8(v.x, true);
    a[2] += __builtin_amdgcn_cvt_pk_f32_fp8(v.y, false);
    a[3] += __builtin_amdgcn_cvt_pk_f32_fp8(v.y, true);
    a[4] += __builtin_amdgcn_cvt_pk_f32_fp8(v.z, false);
    a[5] += __builtin_amdgcn_cvt_pk_f32_fp8(v.z, true);
    a[6] += __builtin_amdgcn_cvt_pk_f32_fp8(v.w, false);
    a[7] += __builtin_amdgcn_cvt_pk_f32_fp8(v.w, true);
}
__device__ __forceinline__ void acc16m(f32x2* a, const uint4 v, float m) {
    f32x2 m2 = {m, m};
    a[0] += m2 * __builtin_amdgcn_cvt_pk_f32_fp8(v.x, false);
    a[1] += m2 * __builtin_amdgcn_cvt_pk_f32_fp8(v.x, true);
    a[2] += m2 * __builtin_amdgcn_cvt_pk_f32_fp8(v.y, false);
    a[3] += m2 * __builtin_amdgcn_cvt_pk_f32_fp8(v.y, true);
    a[4] += m2 * __builtin_amdgcn_cvt_pk_f32_fp8(v.z, false);
    a[5] += m2 * __builtin_amdgcn_cvt_pk_f32_fp8(v.z, true);
    a[6] += m2 * __builtin_amdgcn_cvt_pk_f32_fp8(v.w, false);
    a[7] += m2 * __builtin_amdgcn_cvt_pk_f32_fp8(v.w, true);
}

// Issue the FIRST-16-edge gathers (2 independent uint4 loads, 8 lanes/edge)
// with clamp+mask. Loads stay in flight a full pipeline iteration.
__device__ __forceinline__ void prefetch16q(
        const unsigned char* __restrict__ hwb8, int myidx, int cnt,
        int qg, int ql, uint4& v0, uint4& v1, float& m0, float& m1) {
    int cm = cnt - 1; if (cm < 0) cm = 0;
    int j0 = qg, j1 = 8 + qg;
    m0 = (j0 < cnt) ? 1.f : 0.f;
    m1 = (j1 < cnt) ? 1.f : 0.f;
    if (j0 > cm) j0 = cm;
    if (j1 > cm) j1 = cm;
    int p0 = __shfl(myidx, j0);
    int p1 = __shfl(myidx, j1);
    v0 = *((const uint4*)(hwb8 + (size_t)p0 * 128) + ql);
    v1 = *((const uint4*)(hwb8 + (size_t)p1 * 128) + ql);
}

// Synchronous gather of edges [16, cnt) of a window (prefetch covered 0..15).
__device__ __forceinline__ void gather_rest(
        const unsigned char* __restrict__ hwb8, int myidx, int cnt,
        int qg, int ql, f32x2* a) {
    int i = 16;
    for (; i + 8 <= cnt; i += 8) {
        int p0 = __shfl(myidx, i + qg);
        uint4 v0 = *((const uint4*)(hwb8 + (size_t)p0 * 128) + ql);
        acc16(a, v0);
    }
    int t = cnt - i;
    if (t > 0) {
        int j = i + qg; if (j > cnt - 1) j = cnt - 1;
        int p0 = __shfl(myidx, j);
        uint4 v0 = *((const uint4*)(hwb8 + (size_t)p0 * 128) + ql);
        float m = (qg < t) ? 1.f : 0.f;
        acc16m(a, v0, m);
    }
}

// Full synchronous window gather (extra windows beyond the first 64 edges).
__device__ __forceinline__ void gather_accum(
        const unsigned char* __restrict__ hwb8, int myidx, int cnt,
        int qg, int ql, f32x2* a) {
    int i = 0;
    for (; i + 8 <= cnt; i += 8) {
        int p0 = __shfl(myidx, i + qg);
        uint4 v0 = *((const uint4*)(hwb8 + (size_t)p0 * 128) + ql);
        acc16(a, v0);
    }
    int t = cnt - i;
    if (t > 0) {
        int j = i + qg; if (j > cnt - 1) j = cnt - 1;
        int p0 = __shfl(myidx, j);
        uint4 v0 = *((const uint4*)(hwb8 + (size_t)p0 * 128) + ql);
        float m = (qg < t) ? 1.f : 0.f;
        acc16m(a, v0, m);
    }
}

// Per-dst aggregation, 8-lanes/edge uint4 gathers, 3-stage pipeline,
// reduce-SCATTER over the 8 edge-slots, epilogue over ALL 64 lanes.
__global__ __launch_bounds__(256) void agg_kernel(
        const unsigned char* __restrict__ hwb8, const int* __restrict__ row_ptr,
        const int* __restrict__ blk_sum, const unsigned int* __restrict__ cnt_in,
        const int* __restrict__ csr_src,
        const float* __restrict__ bias, const unsigned short* __restrict__ resb,
        unsigned short* __restrict__ yb, float* __restrict__ parts) {
    __shared__ float red[4 * 256];
    __shared__ int sho[256];
    int tid = threadIdx.x;
    scan_blksum(blk_sum, sho, tid);
    int lane = tid & 63, wid = tid >> 6;
    int wave = blockIdx.x * 4 + wid;
    int nw = AGG_BLOCKS * 4;
    int qg = lane >> 3;                 // edge slot (0..7)
    int ql = lane & 7;                  // 16B segment of the 128B row
    int cp = ql * 8 + qg;               // channel-pair this lane owns post-reduce
    float2 bv = ((const float2*)bias)[cp];
    float s1a = 0.f, s1b = 0.f, s2a = 0.f, s2b = 0.f;

    // pipeline state
    int e0_0 = 0, e1_0 = 0, mi_0 = 0; float ri_0 = 0.f; unsigned int rv_0 = 0u;
    int e0_1 = 0, e1_1 = 0, mi_1 = 0; float ri_1 = 0.f; unsigned int rv_1 = 0u;
    uint4 pv0, pv1; float pm0 = 0.f, pm1 = 0.f;
    pv0 = pv1 = make_uint4(0u, 0u, 0u, 0u);

    int n = wave;
    if (n < N_NODES) {                                 // prologue: S0 state
        e0_0 = row_ptr[n] + BLK_OFF(sho, n >> 9);
        e1_0 = row_ptr[n + 1] + BLK_OFF(sho, (n + 1) >> 9);
        int ci = (int)cnt_in[n];
        ri_0 = rsqrtf((float)(ci > 1 ? ci : 1));
        rv_0 = __builtin_nontemporal_load((const unsigned int*)(resb + (size_t)n * D) + cp);
        int c0 = e1_0 - e0_0; if (c0 > 64) c0 = 64;
        mi_0 = (lane < c0) ? __builtin_nontemporal_load(csr_src + e0_0 + lane) : 0;
        prefetch16q(hwb8, mi_0, c0, qg, ql, pv0, pv1, pm0, pm1);
    }
    int n1g = n + nw;
    if (n1g < N_NODES) {                               // prologue: S1 state
        e0_1 = row_ptr[n1g] + BLK_OFF(sho, n1g >> 9);
        e1_1 = row_ptr[n1g + 1] + BLK_OFF(sho, (n1g + 1) >> 9);
        int ci = (int)cnt_in[n1g];
        ri_1 = rsqrtf((float)(ci > 1 ? ci : 1));
        rv_1 = __builtin_nontemporal_load((const unsigned int*)(resb + (size_t)n1g * D) + cp);
        int c1 = e1_1 - e0_1; if (c1 > 64) c1 = 64;
        mi_1 = (lane < c1) ? __builtin_nontemporal_load(csr_src + e0_1 + lane) : 0;
    }

    while (n < N_NODES) {
        int n2 = n + 2 * nw;
        // ---- stage A: S2 index/meta loads ----
        int e0_2 = 0, e1_2 = 0, mi_2 = 0; float ri_2 = 0.f; unsigned int rv_2 = 0u;
        if (n2 < N_NODES) {
            e0_2 = row_ptr[n2] + BLK_OFF(sho, n2 >> 9);
            e1_2 = row_ptr[n2 + 1] + BLK_OFF(sho, (n2 + 1) >> 9);
            int ci = (int)cnt_in[n2];
            ri_2 = rsqrtf((float)(ci > 1 ? ci : 1));
            rv_2 = __builtin_nontemporal_load((const unsigned int*)(resb + (size_t)n2 * D) + cp);
            int c2 = e1_2 - e0_2; if (c2 > 64) c2 = 64;
            mi_2 = (lane < c2) ? __builtin_nontemporal_load(csr_src + e0_2 + lane) : 0;
        }
        // ---- stage B: S1 first-16 prefetch (mi_1 ready since last iter) ----
        uint4 qv0, qv1; float qm0, qm1;
        {
            int c1 = e1_1 - e0_1; if (c1 > 64) c1 = 64;
            prefetch16q(hwb8, mi_1, c1, qg, ql, qv0, qv1, qm0, qm1);
        }
        // ---- stage C: accumulate S0 ----
        f32x2 a8[8];
        #pragma unroll
        for (int i = 0; i < 8; i++) a8[i] = (f32x2)0.f;
        acc16m(a8, pv0, pm0); acc16m(a8, pv1, pm1);
        {
            int cnt = e1_0 - e0_0; if (cnt > 64) cnt = 64;
            gather_rest(hwb8, mi_0, cnt, qg, ql, a8);
        }
        for (int j0 = e0_0 + 64; j0 < e1_0; j0 += 64) {
            int cnt = e1_0 - j0; if (cnt > 64) cnt = 64;
            int mw = (lane < cnt) ? __builtin_nontemporal_load(csr_src + j0 + lane) : 0;
            gather_accum(hwb8, mw, cnt, qg, ql, a8);
        }
        // ---- reduce-scatter over the 8 edge-slots (xor 8,16,32) ----
        #pragma unroll
        for (int b = 0; b < 3; b++) {
            int half = 4 >> b;
            int bit = (qg >> b) & 1;
            #pragma unroll
            for (int i = 0; i < half; i++) {
                f32x2 keep = bit ? a8[2 * i + 1] : a8[2 * i];
                f32x2 send = bit ? a8[2 * i]     : a8[2 * i + 1];
                f32x2 recv;
                recv.x = __shfl_xor(send.x, 8 << b);
                recv.y = __shfl_xor(send.y, 8 << b);
                a8[i] = keep + recv;
            }
        }
        // ---- epilogue: ALL 64 lanes, 2 channels each ----
        {
            float o0 = fmaxf(a8[0].x * ri_0 + bv.x, 0.f) + bf_lo(rv_0);
            float o1 = fmaxf(a8[0].y * ri_0 + bv.y, 0.f) + bf_hi(rv_0);
            ((unsigned int*)(yb + (size_t)n * D))[cp] = pack_rne(o0, o1);
            s1a += o0; s1b += o1; s2a += o0 * o0; s2b += o1 * o1;
        }
        // ---- rotate pipeline ----
        n += nw;
        e0_0 = e0_1; e1_0 = e1_1; mi_0 = mi_1; ri_0 = ri_1; rv_0 = rv_1;
        e0_1 = e0_2; e1_1 = e1_2; mi_1 = mi_2; ri_1 = ri_2; rv_1 = rv_2;
        pv0 = qv0; pv1 = qv1; pm0 = qm0; pm1 = qm1;
    }
    // BN partial sums: lane owns channels 2cp, 2cp+1
    red[wid * 256 + 2 * cp]           = s1a;
    red[wid * 256 + 2 * cp + 1]       = s1b;
    red[wid * 256 + 128 + 2 * cp]     = s2a;
    red[wid * 256 + 128 + 2 * cp + 1] = s2b;
    __syncthreads();
    if (tid < 256) {
        float v = red[tid] + red[256 + tid] + red[512 + tid] + red[768 + tid];
        parts[(size_t)blockIdx.x * 256 + tid] = v;
    }
}

__global__ __launch_bounds__(256) void bn_fin2(
        const float* __restrict__ parts, const float* __restrict__ gamma,
        const float* __restrict__ beta, float* __restrict__ scsh) {
    __shared__ float rs1[256], rs2[256];
    int c = blockIdx.x, t = threadIdx.x;
    float s1 = 0.f, s2 = 0.f;
    for (int b = t; b < AGG_BLOCKS; b += 256) {
        s1 += parts[(size_t)b * 256 + c];
        s2 += parts[(size_t)b * 256 + 128 + c];
    }
    rs1[t] = s1; rs2[t] = s2;
    __syncthreads();
    for (int off = 128; off > 0; off >>= 1) {
        if (t < off) { rs1[t] += rs1[t + off]; rs2[t] += rs2[t + off]; }
        __syncthreads();
    }
    if (t == 0) {
        const float invN = 1.0f / (float)N_NODES;
        float mean = rs1[0] * invN;
        float var  = rs2[0] * invN - mean * mean;
        float sc = gamma[c] * rsqrtf(var + BN_EPS);
        scsh[c] = sc;
        scsh[128 + c] = beta[c] - mean * sc;
    }
}

__global__ void norm_kernel(const unsigned short* __restrict__ yb,
                            const float* __restrict__ scsh, float* __restrict__ out) {
    int i = blockIdx.x * blockDim.x + threadIdx.x;
    if (i < N_NODES * 16) {
        uint4 v = ((const uint4*)yb)[i];
        int c = (i & 15) * 8;
        f32x4 o0, o1;
        o0[0] = bf_lo(v.x) * scsh[c]     + scsh[128 + c];
        o0[1] = bf_hi(v.x) * scsh[c + 1] + scsh[128 + c + 1];
        o0[2] = bf_lo(v.y) * scsh[c + 2] + scsh[128 + c + 2];
        o0[3] = bf_hi(v.y) * scsh[c + 3] + scsh[128 + c + 3];
        o1[0] = bf_lo(v.z) * scsh[c + 4] + scsh[128 + c + 4];
        o1[1] = bf_hi(v.z) * scsh[c + 5] + scsh[128 + c + 5];
        o1[2] = bf_lo(v.w) * scsh[c + 6] + scsh[128 + c + 6];
        o1[3] = bf_hi(v.w) * scsh[c + 7] + scsh[128 + c + 7];
        f32x4* ov = (f32x4*)out + (size_t)i * 2;
        __builtin_nontemporal_store(o0, ov);
        __builtin_nontemporal_store(o1, ov + 1);
    }
}

extern "C" void kernel_launch(void* const* d_in, const int* in_sizes, int n_in,
                              void* d_out, int out_size, void* d_ws, size_t ws_size,
                              hipStream_t stream) {
    const float* x     = (const float*)d_in[0];
    const int*   src   = (const int*)d_in[1];
    const int*   dst   = (const int*)d_in[2];
    const float* W     = (const float*)d_in[3];
    const float* b     = (const float*)d_in[4];
    const float* Wr    = (const float*)d_in[5];
    const float* br    = (const float*)d_in[6];
    const float* gamma = (const float*)d_in[7];
    const float* beta  = (const float*)d_in[8];
    float* out = (float*)d_out;

    char* ws = (char*)d_ws;
    int*   cnt_in  = (int*)(ws + 0);
    int*   cnt_out = (int*)(ws + 262144);
    int*   row_ptr = (int*)(ws + 524288);
    float* scsh    = (float*)(ws + 1310720);
    int*   blk_sum = (int*)(ws + 1312768);
    int*   csr_src = (int*)(ws + 1576960);
    unsigned char*  hwb8 = (unsigned char*)(ws + 4800000);
    unsigned short* resb = (unsigned short*)(ws + 11200000);
    unsigned short* yb   = (unsigned short*)(ws + 24000000);
    float* parts   = (float*)(ws + 36800000);
    uint4* pW      = (uint4*)(ws + 38897152);
    uint4* pWr     = (uint4*)(ws + 38929920);
    unsigned int* histD = (unsigned int*)(ws + 38962688);
    unsigned int* histS = (unsigned int*)(ws + 45516288);

    hist_kernel<<<dim3(CHUNKS + 16, 4, 2), 256, 0, stream>>>(
        dst, src, histD, histS, W, Wr, pW, pWr);
    merge_kernel<<<dim3(NB_MERGE, 2), 256, 0, stream>>>(
        histD, histS, (int*)cnt_in, (int*)cnt_out, row_ptr, blk_sum);
    gemfill_kernel<<<GEMM_BLKS + FILL_BLKS, 256, 0, stream>>>(
        x, pW, pWr, br, (const unsigned int*)cnt_out, hwb8, resb,
        src, dst, row_ptr, histD, blk_sum, csr_src);
    agg_kernel<<<AGG_BLOCKS, 256, 0, stream>>>(
        hwb8, row_ptr, blk_sum, (const unsigned int*)cnt_in, csr_src, b, resb, yb, parts);
    bn_fin2<<<128, 256, 0, stream>>>(parts, gamma, beta, scsh);
    norm_kernel<<<(N_NODES * 16 + 255) / 256, 256, 0, stream>>>(yb, scsh, out);
}

// Round 12
// 208.239 us; speedup vs baseline: 1.0192x; 1.0192x over previous
//
#include <hip/hip_runtime.h>

#define N_NODES 50000
#define N_EDGES 800000
#define D 128
#define BN_EPS 1e-5f
#define AGG_BLOCKS 2048
#define CHUNKS 64
#define EPC (N_EDGES / CHUNKS)    // 12500 edges per chunk (u16-safe ranks)
#define EPC4 (EPC / 4)            // 3125 int4 loads (chunk base 16B-aligned)
#define QUART_BINS 12800          // node-range quarter
#define QUART_U32 6400            // u32 words per quarter (2 bins/word)
#define NB_MERGE 100              // merge blocks: 512 consecutive nodes each
#define NB_PER_Q 25               // merge blocks per quarter (25*256 = 6400 words)

typedef short bf16x8 __attribute__((ext_vector_type(8)));
typedef float f32x4  __attribute__((ext_vector_type(4)));
typedef float f32x2  __attribute__((ext_vector_type(2)));
typedef unsigned int u32x4 __attribute__((ext_vector_type(4)));
typedef int i32x4 __attribute__((ext_vector_type(4)));   // native vec: nontemporal-safe

// ---------------- workspace layout (bytes) ----------------
// cnt_in @0 (256KB)  cnt_out @262144 (256KB)  row_ptr @524288 (local prefix)
// scsh @1310720  blk_sum @1312768 (100 ints)  csr_src @1576960 (3.2MB)
// hwb8(fp8 [row][col]) @4800000 (6.4MB)  resb(bf16) @11200000 (12.8MB)
// yb @24000000 (12.8MB)  parts @36800000 (2.1MB)
// pW @38897152  pWr @38929920  histD @38962688 (6.55MB)  histS @45516288 (6.55MB)
// hist layout: [(quarter*CHUNKS + chunk)][QUART_U32]

__device__ __forceinline__ unsigned int pack_rne(float a, float b) {
    unsigned int ua = __float_as_uint(a); ua += 0x7fffu + ((ua >> 16) & 1u);
    unsigned int ub = __float_as_uint(b); ub += 0x7fffu + ((ub >> 16) & 1u);
    return (ua >> 16) | (ub & 0xffff0000u);
}
__device__ __forceinline__ unsigned short pack1_rne(float a) {
    unsigned int ua = __float_as_uint(a); ua += 0x7fffu + ((ua >> 16) & 1u);
    return (unsigned short)(ua >> 16);
}
__device__ __forceinline__ unsigned char pack1_fp8(float a) {
    unsigned int u = __builtin_amdgcn_cvt_pk_fp8_f32(a, a, 0, false);
    return (unsigned char)(u & 0xffu);
}

// Shared: per-block LDS scan of the NB_MERGE block totals. sh[] = INCLUSIVE sums.
__device__ __forceinline__ void scan_blksum(const int* __restrict__ blk_sum,
                                            int* sh, int t) {
    int v = (t < NB_MERGE) ? blk_sum[t] : 0;
    if (t < 256) sh[t] = v;
    __syncthreads();
    int inc = v;
    #pragma unroll
    for (int off = 1; off < 256; off <<= 1) {
        int u = (t >= off && t < 256) ? sh[t - off] : 0;
        __syncthreads();
        inc += u;
        if (t < 256) sh[t] = inc;
        __syncthreads();
    }
}
#define BLK_OFF(sh, mb) ((mb) ? (sh)[(mb) - 1] : 0)

// Privatized LDS histogram, grid (chunk[+pack], r-QUARTER, key) = 512 working
// blocks (2/CU), 25.6KB LDS each. int4 edge loads.
// Blocks x >= CHUNKS (y==0,z==0) do the W/Wr pre-pack.
__global__ __launch_bounds__(256) void hist_kernel(
        const int* __restrict__ dst, const int* __restrict__ src,
        unsigned int* __restrict__ histD, unsigned int* __restrict__ histS,
        const float* __restrict__ W, const float* __restrict__ Wr,
        uint4* __restrict__ pW, uint4* __restrict__ pWr) {
    __shared__ unsigned int h[QUART_U32];
    int tid = threadIdx.x;
    int c = blockIdx.x, r = blockIdx.y;
    if (c >= CHUNKS) {
        if (r != 0 || blockIdx.z != 0) return;
        int t = (c - CHUNKS) * 256 + tid;
        const float* S = (t & 2048) ? Wr : W;
        uint4* Dst     = (t & 2048) ? pWr : pW;
        int e = t & 2047;
        int lane = e & 63, ks = (e >> 6) & 3, ct = e >> 8;
        int n  = ct * 16 + (lane & 15);
        int k0 = ks * 32 + (lane >> 4) * 8;
        float v[8];
        #pragma unroll
        for (int j = 0; j < 8; j++) v[j] = S[(k0 + j) * D + n];
        uint4 rr;
        rr.x = pack_rne(v[0], v[1]); rr.y = pack_rne(v[2], v[3]);
        rr.z = pack_rne(v[4], v[5]); rr.w = pack_rne(v[6], v[7]);
        Dst[e] = rr;
        return;
    }
    const int* keys = blockIdx.z ? src : dst;
    unsigned int* hist = blockIdx.z ? histS : histD;
    for (int j = tid; j < QUART_U32; j += 256) h[j] = 0u;
    __syncthreads();
    int lo = r * QUART_BINS;
    const i32x4* keys4 = (const i32x4*)(keys + c * EPC);   // 16B-aligned
    for (int i = tid; i < EPC4; i += 256) {
        i32x4 k = __builtin_nontemporal_load(keys4 + i);
        int b0 = k.x - lo, b1 = k.y - lo, b2 = k.z - lo, b3 = k.w - lo;
        if ((unsigned)b0 < (unsigned)QUART_BINS) atomicAdd(&h[b0 >> 1], 1u << ((b0 & 1) * 16));
        if ((unsigned)b1 < (unsigned)QUART_BINS) atomicAdd(&h[b1 >> 1], 1u << ((b1 & 1) * 16));
        if ((unsigned)b2 < (unsigned)QUART_BINS) atomicAdd(&h[b2 >> 1], 1u << ((b2 & 1) * 16));
        if ((unsigned)b3 < (unsigned)QUART_BINS) atomicAdd(&h[b3 >> 1], 1u << ((b3 & 1) * 16));
    }
    __syncthreads();
    unsigned int* out = hist + ((size_t)(r * CHUNKS + c)) * QUART_U32;
    for (int j = tid; j < QUART_U32; j += 256) out[j] = h[j];
}

// merge, grid (100, key): each block = 256 words = 512 consecutive nodes.
__global__ __launch_bounds__(256) void merge_kernel(
        unsigned int* __restrict__ histD, unsigned int* __restrict__ histS,
        int* __restrict__ cnt_in, int* __restrict__ cnt_out,
        int* __restrict__ row_ptr, int* __restrict__ blk_sum) {
    __shared__ int sh[256];
    int t = threadIdx.x;
    int bx = blockIdx.x;
    int r = bx / NB_PER_Q;
    int q = (bx % NB_PER_Q) * 256 + t;         // word index within quarter
    int n0 = bx * 512 + t * 2;                 // consecutive node id
    if (blockIdx.y) {
        size_t base = (size_t)r * CHUNKS * QUART_U32 + q;
        unsigned int vals[CHUNKS];
        #pragma unroll
        for (int c = 0; c < CHUNKS; c++)
            vals[c] = histS[base + (size_t)c * QUART_U32];   // independent loads
        unsigned int lo = 0, hi = 0;
        #pragma unroll
        for (int c = 0; c < CHUNKS; c++) {
            lo += vals[c] & 0xffffu; hi += vals[c] >> 16;
        }
        cnt_out[n0]     = (int)lo;
        cnt_out[n0 + 1] = (int)hi;
        return;                                // no barriers taken
    }
    size_t base = (size_t)r * CHUNKS * QUART_U32 + q;
    unsigned int vals[CHUNKS];
    #pragma unroll
    for (int c = 0; c < CHUNKS; c++)
        vals[c] = histD[base + (size_t)c * QUART_U32];   // independent loads
    unsigned int lo = 0, hi = 0;
    #pragma unroll
    for (int c = 0; c < CHUNKS; c++) {
        unsigned int v = vals[c];
        histD[base + (size_t)c * QUART_U32] = lo | (hi << 16);  // exclusive prefix
        lo += v & 0xffffu; hi += v >> 16;
    }
    cnt_in[n0]     = (int)lo;
    cnt_in[n0 + 1] = (int)hi;
    // fused intra-block scan over this block's 512 node counts
    int pair = (int)lo + (int)hi;
    sh[t] = pair;
    __syncthreads();
    int inc = pair;
    #pragma unroll
    for (int off = 1; off < 256; off <<= 1) {
        int u = (t >= off) ? sh[t - off] : 0;
        __syncthreads();
        inc += u; sh[t] = inc;
        __syncthreads();
    }
    int excl = inc - pair;
    row_ptr[n0]     = excl;                    // LOCAL prefix (block-relative)
    row_ptr[n0 + 1] = excl + (int)lo;
    if (t == 255) blk_sum[bx] = inc;           // block TOTAL (nodes bx*512..+511)
}

// Counting-sort CSR fill, grid (chunk, bin-QUARTER) = 256 blocks, 512 thr.
// KEY CHANGE (R12): h[b] holds the ABSOLUTE csr base per node-bin (u32),
// initialized in a coalesced pre-pass from row_ptr + blk_off + chunk-prefix.
// Per-edge critical path collapses to ONE LDS atomic-return + scatter store
// (was: atomic + pre_c load + row_ptr load + store).
__global__ __launch_bounds__(512) void fill2_kernel(
        const int* __restrict__ src, const int* __restrict__ dst,
        const int* __restrict__ row_ptr, const unsigned int* __restrict__ histP,
        const int* __restrict__ blk_sum, int* __restrict__ csr_src) {
    __shared__ unsigned int h[QUART_BINS];     // 51.2KB: absolute base per bin
    __shared__ int sho[256];
    int tid = threadIdx.x;
    scan_blksum(blk_sum, sho, tid);
    int c = blockIdx.x, s = blockIdx.y;        // chunk, quarter
    int base = c * EPC;
    int lo = s * QUART_BINS;
    const unsigned int* pre_c = histP + ((size_t)(s * CHUNKS + c)) * QUART_U32;
    for (int b = tid; b < QUART_BINS; b += 512) {
        int d = lo + b;
        unsigned int pre = (pre_c[b >> 1] >> ((b & 1) * 16)) & 0xffffu;
        h[b] = (unsigned int)(row_ptr[d] + BLK_OFF(sho, d >> 9)) + pre;
    }
    __syncthreads();
    for (int i = tid; i < EPC; i += 512) {
        int d = __builtin_nontemporal_load(dst + base + i);
        int b = d - lo;
        if ((unsigned)b < (unsigned)QUART_BINS) {
            unsigned int p = atomicAdd(&h[b], 1u);
            csr_src[p] = __builtin_nontemporal_load(src + base + i);
        }
    }
}

// MFMA dual GEMM, coalesced A-staging through LDS (bf16).
// hwb8 = fp8e4m3(rout*(x@W)) [row][col] (128B rows); resb = bf16(relu(x@Wr+br)).
__global__ __launch_bounds__(256) void gemm_mfma(
        const float* __restrict__ x, const uint4* __restrict__ pW,
        const uint4* __restrict__ pWr, const float* __restrict__ br,
        const unsigned int* __restrict__ cnt_out, unsigned char* __restrict__ hwb8,
        unsigned short* __restrict__ resb) {
    __shared__ unsigned short xs[64][136];
    int tid = threadIdx.x, wid = tid >> 6, lane = tid & 63;
    int quad = lane >> 4, l15 = lane & 15;
    int r0b = blockIdx.x * 64;
    const float4* xg = (const float4*)(x + (size_t)r0b * D);
    int maxidx = (N_NODES - r0b) * (D / 4);
    #pragma unroll
    for (int i = 0; i < 8; i++) {
        int idx = tid + 256 * i;
        float4 v = (idx < maxidx) ? xg[idx] : make_float4(0.f, 0.f, 0.f, 0.f);
        int row = idx >> 5, c0 = (idx & 31) * 4;
        *(unsigned int*)&xs[row][c0]     = pack_rne(v.x, v.y);
        *(unsigned int*)&xs[row][c0 + 2] = pack_rne(v.z, v.w);
    }
    __syncthreads();
    int wrow0 = wid * 16;
    bf16x8 A[4];
    #pragma unroll
    for (int ks = 0; ks < 4; ks++)
        A[ks] = *(const bf16x8*)&xs[wrow0 + l15][ks * 32 + quad * 8];
    f32x4 accW[8], accR[8];
    #pragma unroll
    for (int ct = 0; ct < 8; ct++) { accW[ct] = (f32x4)0.f; accR[ct] = (f32x4)0.f; }
    #pragma unroll
    for (int ct = 0; ct < 8; ct++) {
        #pragma unroll
        for (int ks = 0; ks < 4; ks++) {
            union { bf16x8 v; uint4 u; } Bw, Br2;
            Bw.u  = pW [(ct * 4 + ks) * 64 + lane];
            Br2.u = pWr[(ct * 4 + ks) * 64 + lane];
            accW[ct] = __builtin_amdgcn_mfma_f32_16x16x32_bf16(A[ks], Bw.v,  accW[ct], 0, 0, 0);
            accR[ct] = __builtin_amdgcn_mfma_f32_16x16x32_bf16(A[ks], Br2.v, accR[ct], 0, 0, 0);
        }
    }
    int r0 = r0b + wrow0;
    float ro[4]; int rowok[4];
    #pragma unroll
    for (int reg = 0; reg < 4; reg++) {
        int row = r0 + quad * 4 + reg;
        rowok[reg] = row < N_NODES;
        int cw = (int)cnt_out[rowok[reg] ? row : N_NODES - 1];
        ro[reg] = rsqrtf((float)(cw > 1 ? cw : 1));
    }
    #pragma unroll
    for (int ct = 0; ct < 8; ct++) {
        int c = ct * 16 + l15;
        float brv = br[c];
        #pragma unroll
        for (int reg = 0; reg < 4; reg++) {
            int row = r0 + quad * 4 + reg;
            if (rowok[reg]) {
                hwb8[(size_t)row * D + c] = pack1_fp8(accW[ct][reg] * ro[reg]);
                resb[(size_t)row * D + c] = pack1_rne(fmaxf(accR[ct][reg] + brv, 0.f));
            }
        }
    }
}

__device__ __forceinline__ float bf_lo(unsigned int v) { return __uint_as_float(v << 16); }
__device__ __forceinline__ float bf_hi(unsigned int v) { return __uint_as_float(v & 0xffff0000u); }

// 16-value fp8 accumulate from one uint4 (8 cvt + 8 pk-add)
__device__ __forceinline__ void acc16(f32x2* a, const uint4 v) {
    a[0] += __builtin_amdgcn_cvt_pk_f32_fp8(v.x, false);
    a[1] += __builtin_amdgcn_cvt_pk_f32_fp8(v.x, true);
    a[2] += __builtin_amdgcn_cvt_pk_f32_fp8(v.y, false);
    a[3] += __builtin_amdgcn_cvt_pk_f32_fp8(v.y, true);
    a[4] += __builtin_amdgcn_cvt_pk_f32_fp8(v.z, false);
    a[5] += __builtin_amdgcn_cvt_pk_f32_fp8(v.z, true);
    a[6] += __builtin_amdgcn_cvt_pk_f32_fp8(v.w, false);
    a[7] += __builtin_amdgcn_cvt_pk_f32_fp8(v.w, true);
}
__device__ __forceinline__ void acc16m(f32x2* a, const uint4 v, float m) {
    f32x2 m2 = {m, m};
    a[0] += m2 * __builtin_amdgcn_cvt_pk_f32_fp8(v.x, false);
    a[1] += m2 * __builtin_amdgcn_cvt_pk_f32_fp8(v.x, true);
    a[2] += m2 * __builtin_amdgcn_cvt_pk_f32_fp8(v.y, false);
    a[3] += m2 * __builtin_amdgcn_cvt_pk_f32_fp8(v.y, true);
    a[4] += m2 * __builtin_amdgcn_cvt_pk_f32_fp8(v.z, false);
    a[5] += m2 * __builtin_amdgcn_cvt_pk_f32_fp8(v.z, true);
    a[6] += m2 * __builtin_amdgcn_cvt_pk_f32_fp8(v.w, false);
    a[7] += m2 * __builtin_amdgcn_cvt_pk_f32_fp8(v.w, true);
}

// Issue the FIRST-16-edge gathers (2 independent uint4 loads, 8 lanes/edge)
// with clamp+mask. Loads stay in flight a full pipeline iteration.
__device__ __forceinline__ void prefetch16q(
        const unsigned char* __restrict__ hwb8, int myidx, int cnt,
        int qg, int ql, uint4& v0, uint4& v1, float& m0, float& m1) {
    int cm = cnt - 1; if (cm < 0) cm = 0;
    int j0 = qg, j1 = 8 + qg;
    m0 = (j0 < cnt) ? 1.f : 0.f;
    m1 = (j1 < cnt) ? 1.f : 0.f;
    if (j0 > cm) j0 = cm;
    if (j1 > cm) j1 = cm;
    int p0 = __shfl(myidx, j0);
    int p1 = __shfl(myidx, j1);
    v0 = *((const uint4*)(hwb8 + (size_t)p0 * 128) + ql);
    v1 = *((const uint4*)(hwb8 + (size_t)p1 * 128) + ql);
}

// Synchronous gather of edges [16, cnt) of a window (prefetch covered 0..15).
__device__ __forceinline__ void gather_rest(
        const unsigned char* __restrict__ hwb8, int myidx, int cnt,
        int qg, int ql, f32x2* a) {
    int i = 16;
    for (; i + 8 <= cnt; i += 8) {
        int p0 = __shfl(myidx, i + qg);
        uint4 v0 = *((const uint4*)(hwb8 + (size_t)p0 * 128) + ql);
        acc16(a, v0);
    }
    int t = cnt - i;
    if (t > 0) {
        int j = i + qg; if (j > cnt - 1) j = cnt - 1;
        int p0 = __shfl(myidx, j);
        uint4 v0 = *((const uint4*)(hwb8 + (size_t)p0 * 128) + ql);
        float m = (qg < t) ? 1.f : 0.f;
        acc16m(a, v0, m);
    }
}

// Full synchronous window gather (extra windows beyond the first 64 edges).
__device__ __forceinline__ void gather_accum(
        const unsigned char* __restrict__ hwb8, int myidx, int cnt,
        int qg, int ql, f32x2* a) {
    int i = 0;
    for (; i + 8 <= cnt; i += 8) {
        int p0 = __shfl(myidx, i + qg);
        uint4 v0 = *((const uint4*)(hwb8 + (size_t)p0 * 128) + ql);
        acc16(a, v0);
    }
    int t = cnt - i;
    if (t > 0) {
        int j = i + qg; if (j > cnt - 1) j = cnt - 1;
        int p0 = __shfl(myidx, j);
        uint4 v0 = *((const uint4*)(hwb8 + (size_t)p0 * 128) + ql);
        float m = (qg < t) ? 1.f : 0.f;
        acc16m(a, v0, m);
    }
}

// Per-dst aggregation, 8-lanes/edge uint4 gathers, 3-stage pipeline,
// reduce-SCATTER over the 8 edge-slots, epilogue over ALL 64 lanes.
__global__ __launch_bounds__(256) void agg_kernel(
        const unsigned char* __restrict__ hwb8, const int* __restrict__ row_ptr,
        const int* __restrict__ blk_sum, const unsigned int* __restrict__ cnt_in,
        const int* __restrict__ csr_src,
        const float* __restrict__ bias, const unsigned short* __restrict__ resb,
        unsigned short* __restrict__ yb, float* __restrict__ parts) {
    __shared__ float red[4 * 256];
    __shared__ int sho[256];
    int tid = threadIdx.x;
    scan_blksum(blk_sum, sho, tid);
    int lane = tid & 63, wid = tid >> 6;
    int wave = blockIdx.x * 4 + wid;
    int nw = AGG_BLOCKS * 4;
    int qg = lane >> 3;                 // edge slot (0..7)
    int ql = lane & 7;                  // 16B segment of the 128B row
    int cp = ql * 8 + qg;               // channel-pair this lane owns post-reduce
    float2 bv = ((const float2*)bias)[cp];
    float s1a = 0.f, s1b = 0.f, s2a = 0.f, s2b = 0.f;

    // pipeline state
    int e0_0 = 0, e1_0 = 0, mi_0 = 0; float ri_0 = 0.f; unsigned int rv_0 = 0u;
    int e0_1 = 0, e1_1 = 0, mi_1 = 0; float ri_1 = 0.f; unsigned int rv_1 = 0u;
    uint4 pv0, pv1; float pm0 = 0.f, pm1 = 0.f;
    pv0 = pv1 = make_uint4(0u, 0u, 0u, 0u);

    int n = wave;
    if (n < N_NODES) {                                 // prologue: S0 state
        e0_0 = row_ptr[n] + BLK_OFF(sho, n >> 9);
        e1_0 = row_ptr[n + 1] + BLK_OFF(sho, (n + 1) >> 9);
        int ci = (int)cnt_in[n];
        ri_0 = rsqrtf((float)(ci > 1 ? ci : 1));
        rv_0 = __builtin_nontemporal_load((const unsigned int*)(resb + (size_t)n * D) + cp);
        int c0 = e1_0 - e0_0; if (c0 > 64) c0 = 64;
        mi_0 = (lane < c0) ? __builtin_nontemporal_load(csr_src + e0_0 + lane) : 0;
        prefetch16q(hwb8, mi_0, c0, qg, ql, pv0, pv1, pm0, pm1);
    }
    int n1g = n + nw;
    if (n1g < N_NODES) {                               // prologue: S1 state
        e0_1 = row_ptr[n1g] + BLK_OFF(sho, n1g >> 9);
        e1_1 = row_ptr[n1g + 1] + BLK_OFF(sho, (n1g + 1) >> 9);
        int ci = (int)cnt_in[n1g];
        ri_1 = rsqrtf((float)(ci > 1 ? ci : 1));
        rv_1 = __builtin_nontemporal_load((const unsigned int*)(resb + (size_t)n1g * D) + cp);
        int c1 = e1_1 - e0_1; if (c1 > 64) c1 = 64;
        mi_1 = (lane < c1) ? __builtin_nontemporal_load(csr_src + e0_1 + lane) : 0;
    }

    while (n < N_NODES) {
        int n2 = n + 2 * nw;
        // ---- stage A: S2 index/meta loads ----
        int e0_2 = 0, e1_2 = 0, mi_2 = 0; float ri_2 = 0.f; unsigned int rv_2 = 0u;
        if (n2 < N_NODES) {
            e0_2 = row_ptr[n2] + BLK_OFF(sho, n2 >> 9);
            e1_2 = row_ptr[n2 + 1] + BLK_OFF(sho, (n2 + 1) >> 9);
            int ci = (int)cnt_in[n2];
            ri_2 = rsqrtf((float)(ci > 1 ? ci : 1));
            rv_2 = __builtin_nontemporal_load((const unsigned int*)(resb + (size_t)n2 * D) + cp);
            int c2 = e1_2 - e0_2; if (c2 > 64) c2 = 64;
            mi_2 = (lane < c2) ? __builtin_nontemporal_load(csr_src + e0_2 + lane) : 0;
        }
        // ---- stage B: S1 first-16 prefetch (mi_1 ready since last iter) ----
        uint4 qv0, qv1; float qm0, qm1;
        {
            int c1 = e1_1 - e0_1; if (c1 > 64) c1 = 64;
            prefetch16q(hwb8, mi_1, c1, qg, ql, qv0, qv1, qm0, qm1);
        }
        // ---- stage C: accumulate S0 ----
        f32x2 a8[8];
        #pragma unroll
        for (int i = 0; i < 8; i++) a8[i] = (f32x2)0.f;
        acc16m(a8, pv0, pm0); acc16m(a8, pv1, pm1);
        {
            int cnt = e1_0 - e0_0; if (cnt > 64) cnt = 64;
            gather_rest(hwb8, mi_0, cnt, qg, ql, a8);
        }
        for (int j0 = e0_0 + 64; j0 < e1_0; j0 += 64) {
            int cnt = e1_0 - j0; if (cnt > 64) cnt = 64;
            int mw = (lane < cnt) ? __builtin_nontemporal_load(csr_src + j0 + lane) : 0;
            gather_accum(hwb8, mw, cnt, qg, ql, a8);
        }
        // ---- reduce-scatter over the 8 edge-slots (xor 8,16,32) ----
        #pragma unroll
        for (int b = 0; b < 3; b++) {
            int half = 4 >> b;
            int bit = (qg >> b) & 1;
            #pragma unroll
            for (int i = 0; i < half; i++) {
                f32x2 keep = bit ? a8[2 * i + 1] : a8[2 * i];
                f32x2 send = bit ? a8[2 * i]     : a8[2 * i + 1];
                f32x2 recv;
                recv.x = __shfl_xor(send.x, 8 << b);
                recv.y = __shfl_xor(send.y, 8 << b);
                a8[i] = keep + recv;
            }
        }
        // ---- epilogue: ALL 64 lanes, 2 channels each ----
        {
            float o0 = fmaxf(a8[0].x * ri_0 + bv.x, 0.f) + bf_lo(rv_0);
            float o1 = fmaxf(a8[0].y * ri_0 + bv.y, 0.f) + bf_hi(rv_0);
            ((unsigned int*)(yb + (size_t)n * D))[cp] = pack_rne(o0, o1);
            s1a += o0; s1b += o1; s2a += o0 * o0; s2b += o1 * o1;
        }
        // ---- rotate pipeline ----
        n += nw;
        e0_0 = e0_1; e1_0 = e1_1; mi_0 = mi_1; ri_0 = ri_1; rv_0 = rv_1;
        e0_1 = e0_2; e1_1 = e1_2; mi_1 = mi_2; ri_1 = ri_2; rv_1 = rv_2;
        pv0 = qv0; pv1 = qv1; pm0 = qm0; pm1 = qm1;
    }
    // BN partial sums: lane owns channels 2cp, 2cp+1
    red[wid * 256 + 2 * cp]           = s1a;
    red[wid * 256 + 2 * cp + 1]       = s1b;
    red[wid * 256 + 128 + 2 * cp]     = s2a;
    red[wid * 256 + 128 + 2 * cp + 1] = s2b;
    __syncthreads();
    if (tid < 256) {
        float v = red[tid] + red[256 + tid] + red[512 + tid] + red[768 + tid];
        parts[(size_t)blockIdx.x * 256 + tid] = v;
    }
}

__global__ __launch_bounds__(256) void bn_fin2(
        const float* __restrict__ parts, const float* __restrict__ gamma,
        const float* __restrict__ beta, float* __restrict__ scsh) {
    __shared__ float rs1[256], rs2[256];
    int c = blockIdx.x, t = threadIdx.x;
    float s1 = 0.f, s2 = 0.f;
    for (int b = t; b < AGG_BLOCKS; b += 256) {
        s1 += parts[(size_t)b * 256 + c];
        s2 += parts[(size_t)b * 256 + 128 + c];
    }
    rs1[t] = s1; rs2[t] = s2;
    __syncthreads();
    for (int off = 128; off > 0; off >>= 1) {
        if (t < off) { rs1[t] += rs1[t + off]; rs2[t] += rs2[t + off]; }
        __syncthreads();
    }
    if (t == 0) {
        const float invN = 1.0f / (float)N_NODES;
        float mean = rs1[0] * invN;
        float var  = rs2[0] * invN - mean * mean;
        float sc = gamma[c] * rsqrtf(var + BN_EPS);
        scsh[c] = sc;
        scsh[128 + c] = beta[c] - mean * sc;
    }
}

__global__ void norm_kernel(const unsigned short* __restrict__ yb,
                            const float* __restrict__ scsh, float* __restrict__ out) {
    int i = blockIdx.x * blockDim.x + threadIdx.x;
    if (i < N_NODES * 16) {
        uint4 v = ((const uint4*)yb)[i];
        int c = (i & 15) * 8;
        f32x4 o0, o1;
        o0[0] = bf_lo(v.x) * scsh[c]     + scsh[128 + c];
        o0[1] = bf_hi(v.x) * scsh[c + 1] + scsh[128 + c + 1];
        o0[2] = bf_lo(v.y) * scsh[c + 2] + scsh[128 + c + 2];
        o0[3] = bf_hi(v.y) * scsh[c + 3] + scsh[128 + c + 3];
        o1[0] = bf_lo(v.z) * scsh[c + 4] + scsh[128 + c + 4];
        o1[1] = bf_hi(v.z) * scsh[c + 5] + scsh[128 + c + 5];
        o1[2] = bf_lo(v.w) * scsh[c + 6] + scsh[128 + c + 6];
        o1[3] = bf_hi(v.w) * scsh[c + 7] + scsh[128 + c + 7];
        f32x4* ov = (f32x4*)out + (size_t)i * 2;
        __builtin_nontemporal_store(o0, ov);
        __builtin_nontemporal_store(o1, ov + 1);
    }
}

extern "C" void kernel_launch(void* const* d_in, const int* in_sizes, int n_in,
                              void* d_out, int out_size, void* d_ws, size_t ws_size,
                              hipStream_t stream) {
    const float* x     = (const float*)d_in[0];
    const int*   src   = (const int*)d_in[1];
    const int*   dst   = (const int*)d_in[2];
    const float* W     = (const float*)d_in[3];
    const float* b     = (const float*)d_in[4];
    const float* Wr    = (const float*)d_in[5];
    const float* br    = (const float*)d_in[6];
    const float* gamma = (const float*)d_in[7];
    const float* beta  = (const float*)d_in[8];
    float* out = (float*)d_out;

    char* ws = (char*)d_ws;
    int*   cnt_in  = (int*)(ws + 0);
    int*   cnt_out = (int*)(ws + 262144);
    int*   row_ptr = (int*)(ws + 524288);
    float* scsh    = (float*)(ws + 1310720);
    int*   blk_sum = (int*)(ws + 1312768);
    int*   csr_src = (int*)(ws + 1576960);
    unsigned char*  hwb8 = (unsigned char*)(ws + 4800000);
    unsigned short* resb = (unsigned short*)(ws + 11200000);
    unsigned short* yb   = (unsigned short*)(ws + 24000000);
    float* parts   = (float*)(ws + 36800000);
    uint4* pW      = (uint4*)(ws + 38897152);
    uint4* pWr     = (uint4*)(ws + 38929920);
    unsigned int* histD = (unsigned int*)(ws + 38962688);
    unsigned int* histS = (unsigned int*)(ws + 45516288);

    hist_kernel<<<dim3(CHUNKS + 16, 4, 2), 256, 0, stream>>>(
        dst, src, histD, histS, W, Wr, pW, pWr);
    merge_kernel<<<dim3(NB_MERGE, 2), 256, 0, stream>>>(
        histD, histS, (int*)cnt_in, (int*)cnt_out, row_ptr, blk_sum);
    fill2_kernel<<<dim3(CHUNKS, 4), 512, 0, stream>>>(
        src, dst, row_ptr, histD, blk_sum, csr_src);
    gemm_mfma<<<(N_NODES + 63) / 64, 256, 0, stream>>>(
        x, pW, pWr, br, (const unsigned int*)cnt_out, hwb8, resb);
    agg_kernel<<<AGG_BLOCKS, 256, 0, stream>>>(
        hwb8, row_ptr, blk_sum, (const unsigned int*)cnt_in, csr_src, b, resb, yb, parts);
    bn_fin2<<<128, 256, 0, stream>>>(parts, gamma, beta, scsh);
    norm_kernel<<<(N_NODES * 16 + 255) / 256, 256, 0, stream>>>(yb, scsh, out);
}

// Round 13
// 207.988 us; speedup vs baseline: 1.0204x; 1.0012x over previous
//
#include <hip/hip_runtime.h>

#define N_NODES 50000
#define N_EDGES 800000
#define D 128
#define BN_EPS 1e-5f
#define AGG_BLOCKS 2048
#define CHUNKS 64
#define EPC (N_EDGES / CHUNKS)    // 12500 edges per chunk (u16-safe ranks)
#define EPC4 (EPC / 4)            // 3125 int4 loads (chunk base 16B-aligned)
#define QUART_BINS 12800          // node-range quarter
#define QUART_U32 6400            // u32 words per quarter (2 bins/word)
#define NB_MERGE 100              // merge blocks: 512 consecutive nodes each
#define NB_PER_Q 25               // merge blocks per quarter (25*256 = 6400 words)

typedef short bf16x8 __attribute__((ext_vector_type(8)));
typedef float f32x4  __attribute__((ext_vector_type(4)));
typedef float f32x2  __attribute__((ext_vector_type(2)));
typedef unsigned int u32x4 __attribute__((ext_vector_type(4)));
typedef int i32x4 __attribute__((ext_vector_type(4)));   // native vec: nontemporal-safe

// ---------------- workspace layout (bytes) ----------------
// cnt_in @0 (256KB)  cnt_out @262144 (256KB)  row_ptr @524288 (local prefix)
// scsh @1310720  blk_sum @1312768 (100 ints)  csr_src @1576960 (3.2MB)
// hwb8(fp8 [row][col]) @4800000 (6.4MB)  resb(bf16) @11200000 (12.8MB)
// yb @24000000 (12.8MB)  parts @36800000 (2.1MB)
// pW @38897152  pWr @38929920  histD @38962688 (6.55MB)  histS @45516288 (6.55MB)
// hist layout: [(quarter*CHUNKS + chunk)][QUART_U32]

__device__ __forceinline__ unsigned int pack_rne(float a, float b) {
    unsigned int ua = __float_as_uint(a); ua += 0x7fffu + ((ua >> 16) & 1u);
    unsigned int ub = __float_as_uint(b); ub += 0x7fffu + ((ub >> 16) & 1u);
    return (ua >> 16) | (ub & 0xffff0000u);
}
__device__ __forceinline__ unsigned short pack1_rne(float a) {
    unsigned int ua = __float_as_uint(a); ua += 0x7fffu + ((ua >> 16) & 1u);
    return (unsigned short)(ua >> 16);
}
__device__ __forceinline__ unsigned char pack1_fp8(float a) {
    unsigned int u = __builtin_amdgcn_cvt_pk_fp8_f32(a, a, 0, false);
    return (unsigned char)(u & 0xffu);
}

// Shared: per-block LDS scan of the NB_MERGE block totals. sh[] = INCLUSIVE sums.
__device__ __forceinline__ void scan_blksum(const int* __restrict__ blk_sum,
                                            int* sh, int t) {
    int v = (t < NB_MERGE) ? blk_sum[t] : 0;
    if (t < 256) sh[t] = v;
    __syncthreads();
    int inc = v;
    #pragma unroll
    for (int off = 1; off < 256; off <<= 1) {
        int u = (t >= off && t < 256) ? sh[t - off] : 0;
        __syncthreads();
        inc += u;
        if (t < 256) sh[t] = inc;
        __syncthreads();
    }
}
#define BLK_OFF(sh, mb) ((mb) ? (sh)[(mb) - 1] : 0)

// Privatized LDS histogram, grid (chunk[+pack], r-QUARTER, key) = 512 working
// blocks (2/CU), 25.6KB LDS each. int4 edge loads.
// Blocks x >= CHUNKS (y==0,z==0) do the W/Wr pre-pack.
__global__ __launch_bounds__(256) void hist_kernel(
        const int* __restrict__ dst, const int* __restrict__ src,
        unsigned int* __restrict__ histD, unsigned int* __restrict__ histS,
        const float* __restrict__ W, const float* __restrict__ Wr,
        uint4* __restrict__ pW, uint4* __restrict__ pWr) {
    __shared__ unsigned int h[QUART_U32];
    int tid = threadIdx.x;
    int c = blockIdx.x, r = blockIdx.y;
    if (c >= CHUNKS) {
        if (r != 0 || blockIdx.z != 0) return;
        int t = (c - CHUNKS) * 256 + tid;
        const float* S = (t & 2048) ? Wr : W;
        uint4* Dst     = (t & 2048) ? pWr : pW;
        int e = t & 2047;
        int lane = e & 63, ks = (e >> 6) & 3, ct = e >> 8;
        int n  = ct * 16 + (lane & 15);
        int k0 = ks * 32 + (lane >> 4) * 8;
        float v[8];
        #pragma unroll
        for (int j = 0; j < 8; j++) v[j] = S[(k0 + j) * D + n];
        uint4 rr;
        rr.x = pack_rne(v[0], v[1]); rr.y = pack_rne(v[2], v[3]);
        rr.z = pack_rne(v[4], v[5]); rr.w = pack_rne(v[6], v[7]);
        Dst[e] = rr;
        return;
    }
    const int* keys = blockIdx.z ? src : dst;
    unsigned int* hist = blockIdx.z ? histS : histD;
    for (int j = tid; j < QUART_U32; j += 256) h[j] = 0u;
    __syncthreads();
    int lo = r * QUART_BINS;
    const i32x4* keys4 = (const i32x4*)(keys + c * EPC);   // 16B-aligned
    for (int i = tid; i < EPC4; i += 256) {
        i32x4 k = __builtin_nontemporal_load(keys4 + i);
        int b0 = k.x - lo, b1 = k.y - lo, b2 = k.z - lo, b3 = k.w - lo;
        if ((unsigned)b0 < (unsigned)QUART_BINS) atomicAdd(&h[b0 >> 1], 1u << ((b0 & 1) * 16));
        if ((unsigned)b1 < (unsigned)QUART_BINS) atomicAdd(&h[b1 >> 1], 1u << ((b1 & 1) * 16));
        if ((unsigned)b2 < (unsigned)QUART_BINS) atomicAdd(&h[b2 >> 1], 1u << ((b2 & 1) * 16));
        if ((unsigned)b3 < (unsigned)QUART_BINS) atomicAdd(&h[b3 >> 1], 1u << ((b3 & 1) * 16));
    }
    __syncthreads();
    unsigned int* out = hist + ((size_t)(r * CHUNKS + c)) * QUART_U32;
    for (int j = tid; j < QUART_U32; j += 256) out[j] = h[j];
}

// merge, grid (100, key): each block = 256 words = 512 consecutive nodes.
__global__ __launch_bounds__(256) void merge_kernel(
        unsigned int* __restrict__ histD, unsigned int* __restrict__ histS,
        int* __restrict__ cnt_in, int* __restrict__ cnt_out,
        int* __restrict__ row_ptr, int* __restrict__ blk_sum) {
    __shared__ int sh[256];
    int t = threadIdx.x;
    int bx = blockIdx.x;
    int r = bx / NB_PER_Q;
    int q = (bx % NB_PER_Q) * 256 + t;         // word index within quarter
    int n0 = bx * 512 + t * 2;                 // consecutive node id
    if (blockIdx.y) {
        size_t base = (size_t)r * CHUNKS * QUART_U32 + q;
        unsigned int vals[CHUNKS];
        #pragma unroll
        for (int c = 0; c < CHUNKS; c++)
            vals[c] = histS[base + (size_t)c * QUART_U32];   // independent loads
        unsigned int lo = 0, hi = 0;
        #pragma unroll
        for (int c = 0; c < CHUNKS; c++) {
            lo += vals[c] & 0xffffu; hi += vals[c] >> 16;
        }
        cnt_out[n0]     = (int)lo;
        cnt_out[n0 + 1] = (int)hi;
        return;                                // no barriers taken
    }
    size_t base = (size_t)r * CHUNKS * QUART_U32 + q;
    unsigned int vals[CHUNKS];
    #pragma unroll
    for (int c = 0; c < CHUNKS; c++)
        vals[c] = histD[base + (size_t)c * QUART_U32];   // independent loads
    unsigned int lo = 0, hi = 0;
    #pragma unroll
    for (int c = 0; c < CHUNKS; c++) {
        unsigned int v = vals[c];
        histD[base + (size_t)c * QUART_U32] = lo | (hi << 16);  // exclusive prefix
        lo += v & 0xffffu; hi += v >> 16;
    }
    cnt_in[n0]     = (int)lo;
    cnt_in[n0 + 1] = (int)hi;
    // fused intra-block scan over this block's 512 node counts
    int pair = (int)lo + (int)hi;
    sh[t] = pair;
    __syncthreads();
    int inc = pair;
    #pragma unroll
    for (int off = 1; off < 256; off <<= 1) {
        int u = (t >= off) ? sh[t - off] : 0;
        __syncthreads();
        inc += u; sh[t] = inc;
        __syncthreads();
    }
    int excl = inc - pair;
    row_ptr[n0]     = excl;                    // LOCAL prefix (block-relative)
    row_ptr[n0 + 1] = excl + (int)lo;
    if (t == 255) blk_sum[bx] = inc;           // block TOTAL (nodes bx*512..+511)
}

// Counting-sort CSR fill, grid (chunk, bin-QUARTER) = 256 blocks, 512 thr.
// h[b] holds the ABSOLUTE csr base per node-bin (u32), initialized in a
// coalesced pre-pass; per-edge path = ONE LDS atomic-return + scatter store.
__global__ __launch_bounds__(512) void fill2_kernel(
        const int* __restrict__ src, const int* __restrict__ dst,
        const int* __restrict__ row_ptr, const unsigned int* __restrict__ histP,
        const int* __restrict__ blk_sum, int* __restrict__ csr_src) {
    __shared__ unsigned int h[QUART_BINS];     // 51.2KB: absolute base per bin
    __shared__ int sho[256];
    int tid = threadIdx.x;
    scan_blksum(blk_sum, sho, tid);
    int c = blockIdx.x, s = blockIdx.y;        // chunk, quarter
    int base = c * EPC;
    int lo = s * QUART_BINS;
    const unsigned int* pre_c = histP + ((size_t)(s * CHUNKS + c)) * QUART_U32;
    for (int b = tid; b < QUART_BINS; b += 512) {
        int d = lo + b;
        unsigned int pre = (pre_c[b >> 1] >> ((b & 1) * 16)) & 0xffffu;
        h[b] = (unsigned int)(row_ptr[d] + BLK_OFF(sho, d >> 9)) + pre;
    }
    __syncthreads();
    for (int i = tid; i < EPC; i += 512) {
        int d = __builtin_nontemporal_load(dst + base + i);
        int b = d - lo;
        if ((unsigned)b < (unsigned)QUART_BINS) {
            unsigned int p = atomicAdd(&h[b], 1u);
            csr_src[p] = __builtin_nontemporal_load(src + base + i);
        }
    }
}

// MFMA dual GEMM, coalesced A-staging through LDS (bf16).
// hwb8 = fp8e4m3(rout*(x@W)) [row][col] (128B rows); resb = bf16(relu(x@Wr+br)).
__global__ __launch_bounds__(256) void gemm_mfma(
        const float* __restrict__ x, const uint4* __restrict__ pW,
        const uint4* __restrict__ pWr, const float* __restrict__ br,
        const unsigned int* __restrict__ cnt_out, unsigned char* __restrict__ hwb8,
        unsigned short* __restrict__ resb) {
    __shared__ unsigned short xs[64][136];
    int tid = threadIdx.x, wid = tid >> 6, lane = tid & 63;
    int quad = lane >> 4, l15 = lane & 15;
    int r0b = blockIdx.x * 64;
    const float4* xg = (const float4*)(x + (size_t)r0b * D);
    int maxidx = (N_NODES - r0b) * (D / 4);
    #pragma unroll
    for (int i = 0; i < 8; i++) {
        int idx = tid + 256 * i;
        float4 v = (idx < maxidx) ? xg[idx] : make_float4(0.f, 0.f, 0.f, 0.f);
        int row = idx >> 5, c0 = (idx & 31) * 4;
        *(unsigned int*)&xs[row][c0]     = pack_rne(v.x, v.y);
        *(unsigned int*)&xs[row][c0 + 2] = pack_rne(v.z, v.w);
    }
    __syncthreads();
    int wrow0 = wid * 16;
    bf16x8 A[4];
    #pragma unroll
    for (int ks = 0; ks < 4; ks++)
        A[ks] = *(const bf16x8*)&xs[wrow0 + l15][ks * 32 + quad * 8];
    f32x4 accW[8], accR[8];
    #pragma unroll
    for (int ct = 0; ct < 8; ct++) { accW[ct] = (f32x4)0.f; accR[ct] = (f32x4)0.f; }
    #pragma unroll
    for (int ct = 0; ct < 8; ct++) {
        #pragma unroll
        for (int ks = 0; ks < 4; ks++) {
            union { bf16x8 v; uint4 u; } Bw, Br2;
            Bw.u  = pW [(ct * 4 + ks) * 64 + lane];
            Br2.u = pWr[(ct * 4 + ks) * 64 + lane];
            accW[ct] = __builtin_amdgcn_mfma_f32_16x16x32_bf16(A[ks], Bw.v,  accW[ct], 0, 0, 0);
            accR[ct] = __builtin_amdgcn_mfma_f32_16x16x32_bf16(A[ks], Br2.v, accR[ct], 0, 0, 0);
        }
    }
    int r0 = r0b + wrow0;
    float ro[4]; int rowok[4];
    #pragma unroll
    for (int reg = 0; reg < 4; reg++) {
        int row = r0 + quad * 4 + reg;
        rowok[reg] = row < N_NODES;
        int cw = (int)cnt_out[rowok[reg] ? row : N_NODES - 1];
        ro[reg] = rsqrtf((float)(cw > 1 ? cw : 1));
    }
    #pragma unroll
    for (int ct = 0; ct < 8; ct++) {
        int c = ct * 16 + l15;
        float brv = br[c];
        #pragma unroll
        for (int reg = 0; reg < 4; reg++) {
            int row = r0 + quad * 4 + reg;
            if (rowok[reg]) {
                hwb8[(size_t)row * D + c] = pack1_fp8(accW[ct][reg] * ro[reg]);
                resb[(size_t)row * D + c] = pack1_rne(fmaxf(accR[ct][reg] + brv, 0.f));
            }
        }
    }
}

__device__ __forceinline__ float bf_lo(unsigned int v) { return __uint_as_float(v << 16); }
__device__ __forceinline__ float bf_hi(unsigned int v) { return __uint_as_float(v & 0xffff0000u); }

// 16-value fp8 accumulate from one uint4 (8 cvt + 8 pk-add)
__device__ __forceinline__ void acc16(f32x2* a, const uint4 v) {
    a[0] += __builtin_amdgcn_cvt_pk_f32_fp8(v.x, false);
    a[1] += __builtin_amdgcn_cvt_pk_f32_fp8(v.x, true);
    a[2] += __builtin_amdgcn_cvt_pk_f32_fp8(v.y, false);
    a[3] += __builtin_amdgcn_cvt_pk_f32_fp8(v.y, true);
    a[4] += __builtin_amdgcn_cvt_pk_f32_fp8(v.z, false);
    a[5] += __builtin_amdgcn_cvt_pk_f32_fp8(v.z, true);
    a[6] += __builtin_amdgcn_cvt_pk_f32_fp8(v.w, false);
    a[7] += __builtin_amdgcn_cvt_pk_f32_fp8(v.w, true);
}
__device__ __forceinline__ void acc16m(f32x2* a, const uint4 v, float m) {
    f32x2 m2 = {m, m};
    a[0] += m2 * __builtin_amdgcn_cvt_pk_f32_fp8(v.x, false);
    a[1] += m2 * __builtin_amdgcn_cvt_pk_f32_fp8(v.x, true);
    a[2] += m2 * __builtin_amdgcn_cvt_pk_f32_fp8(v.y, false);
    a[3] += m2 * __builtin_amdgcn_cvt_pk_f32_fp8(v.y, true);
    a[4] += m2 * __builtin_amdgcn_cvt_pk_f32_fp8(v.z, false);
    a[5] += m2 * __builtin_amdgcn_cvt_pk_f32_fp8(v.z, true);
    a[6] += m2 * __builtin_amdgcn_cvt_pk_f32_fp8(v.w, false);
    a[7] += m2 * __builtin_amdgcn_cvt_pk_f32_fp8(v.w, true);
}

// Issue the FIRST-32-edge gathers (2 + 2-guarded uint4 loads, 8 lanes/edge).
// cnt is WAVE-UNIFORM (one node per wave) so the upper-half issue is a
// uniform branch: deg<=16 nodes pay exactly R10's cost; deg 17-32 nodes get
// their gathers pipelined instead of an exposed sync round (~98% coverage).
__device__ __forceinline__ void prefetch32q(
        const unsigned char* __restrict__ hwb8, int myidx, int cnt,
        int qg, int ql, uint4* v, float* m) {
    int cm = cnt - 1; if (cm < 0) cm = 0;
    int j0 = qg, j1 = 8 + qg;
    m[0] = (j0 < cnt) ? 1.f : 0.f;
    m[1] = (j1 < cnt) ? 1.f : 0.f;
    if (j0 > cm) j0 = cm;
    if (j1 > cm) j1 = cm;
    int p0 = __shfl(myidx, j0);
    int p1 = __shfl(myidx, j1);
    v[0] = *((const uint4*)(hwb8 + (size_t)p0 * 128) + ql);
    v[1] = *((const uint4*)(hwb8 + (size_t)p1 * 128) + ql);
    v[2] = v[3] = make_uint4(0u, 0u, 0u, 0u);
    m[2] = m[3] = 0.f;
    if (cnt > 16) {                            // wave-uniform branch
        int j2 = 16 + qg, j3 = 24 + qg;
        m[2] = (j2 < cnt) ? 1.f : 0.f;
        m[3] = (j3 < cnt) ? 1.f : 0.f;
        if (j2 > cm) j2 = cm;
        if (j3 > cm) j3 = cm;
        int p2 = __shfl(myidx, j2);
        int p3 = __shfl(myidx, j3);
        v[2] = *((const uint4*)(hwb8 + (size_t)p2 * 128) + ql);
        v[3] = *((const uint4*)(hwb8 + (size_t)p3 * 128) + ql);
    }
}

// Synchronous gather of edges [32, cnt) of a window (prefetch covered 0..31).
__device__ __forceinline__ void gather_rest(
        const unsigned char* __restrict__ hwb8, int myidx, int cnt,
        int qg, int ql, f32x2* a) {
    int i = 32;
    for (; i + 8 <= cnt; i += 8) {
        int p0 = __shfl(myidx, i + qg);
        uint4 v0 = *((const uint4*)(hwb8 + (size_t)p0 * 128) + ql);
        acc16(a, v0);
    }
    int t = cnt - i;
    if (t > 0) {
        int j = i + qg; if (j > cnt - 1) j = cnt - 1;
        int p0 = __shfl(myidx, j);
        uint4 v0 = *((const uint4*)(hwb8 + (size_t)p0 * 128) + ql);
        float m = (qg < t) ? 1.f : 0.f;
        acc16m(a, v0, m);
    }
}

// Full synchronous window gather (extra windows beyond the first 64 edges).
__device__ __forceinline__ void gather_accum(
        const unsigned char* __restrict__ hwb8, int myidx, int cnt,
        int qg, int ql, f32x2* a) {
    int i = 0;
    for (; i + 8 <= cnt; i += 8) {
        int p0 = __shfl(myidx, i + qg);
        uint4 v0 = *((const uint4*)(hwb8 + (size_t)p0 * 128) + ql);
        acc16(a, v0);
    }
    int t = cnt - i;
    if (t > 0) {
        int j = i + qg; if (j > cnt - 1) j = cnt - 1;
        int p0 = __shfl(myidx, j);
        uint4 v0 = *((const uint4*)(hwb8 + (size_t)p0 * 128) + ql);
        float m = (qg < t) ? 1.f : 0.f;
        acc16m(a, v0, m);
    }
}

// Per-dst aggregation, 8-lanes/edge uint4 gathers, 3-stage pipeline with
// guarded 32-edge prefetch, reduce-SCATTER, epilogue over ALL 64 lanes.
__global__ __launch_bounds__(256) void agg_kernel(
        const unsigned char* __restrict__ hwb8, const int* __restrict__ row_ptr,
        const int* __restrict__ blk_sum, const unsigned int* __restrict__ cnt_in,
        const int* __restrict__ csr_src,
        const float* __restrict__ bias, const unsigned short* __restrict__ resb,
        unsigned short* __restrict__ yb, float* __restrict__ parts) {
    __shared__ float red[4 * 256];
    __shared__ int sho[256];
    int tid = threadIdx.x;
    scan_blksum(blk_sum, sho, tid);
    int lane = tid & 63, wid = tid >> 6;
    int wave = blockIdx.x * 4 + wid;
    int nw = AGG_BLOCKS * 4;
    int qg = lane >> 3;                 // edge slot (0..7)
    int ql = lane & 7;                  // 16B segment of the 128B row
    int cp = ql * 8 + qg;               // channel-pair this lane owns post-reduce
    float2 bv = ((const float2*)bias)[cp];
    float s1a = 0.f, s1b = 0.f, s2a = 0.f, s2b = 0.f;

    // pipeline state
    int e0_0 = 0, e1_0 = 0, mi_0 = 0; float ri_0 = 0.f; unsigned int rv_0 = 0u;
    int e0_1 = 0, e1_1 = 0, mi_1 = 0; float ri_1 = 0.f; unsigned int rv_1 = 0u;
    uint4 pv[4]; float pm[4];
    #pragma unroll
    for (int i = 0; i < 4; i++) { pv[i] = make_uint4(0u, 0u, 0u, 0u); pm[i] = 0.f; }

    int n = wave;
    if (n < N_NODES) {                                 // prologue: S0 state
        e0_0 = row_ptr[n] + BLK_OFF(sho, n >> 9);
        e1_0 = row_ptr[n + 1] + BLK_OFF(sho, (n + 1) >> 9);
        int ci = (int)cnt_in[n];
        ri_0 = rsqrtf((float)(ci > 1 ? ci : 1));
        rv_0 = __builtin_nontemporal_load((const unsigned int*)(resb + (size_t)n * D) + cp);
        int c0 = e1_0 - e0_0; if (c0 > 64) c0 = 64;
        mi_0 = (lane < c0) ? __builtin_nontemporal_load(csr_src + e0_0 + lane) : 0;
        prefetch32q(hwb8, mi_0, c0, qg, ql, pv, pm);
    }
    int n1g = n + nw;
    if (n1g < N_NODES) {                               // prologue: S1 state
        e0_1 = row_ptr[n1g] + BLK_OFF(sho, n1g >> 9);
        e1_1 = row_ptr[n1g + 1] + BLK_OFF(sho, (n1g + 1) >> 9);
        int ci = (int)cnt_in[n1g];
        ri_1 = rsqrtf((float)(ci > 1 ? ci : 1));
        rv_1 = __builtin_nontemporal_load((const unsigned int*)(resb + (size_t)n1g * D) + cp);
        int c1 = e1_1 - e0_1; if (c1 > 64) c1 = 64;
        mi_1 = (lane < c1) ? __builtin_nontemporal_load(csr_src + e0_1 + lane) : 0;
    }

    while (n < N_NODES) {
        int n2 = n + 2 * nw;
        // ---- stage A: S2 index/meta loads ----
        int e0_2 = 0, e1_2 = 0, mi_2 = 0; float ri_2 = 0.f; unsigned int rv_2 = 0u;
        if (n2 < N_NODES) {
            e0_2 = row_ptr[n2] + BLK_OFF(sho, n2 >> 9);
            e1_2 = row_ptr[n2 + 1] + BLK_OFF(sho, (n2 + 1) >> 9);
            int ci = (int)cnt_in[n2];
            ri_2 = rsqrtf((float)(ci > 1 ? ci : 1));
            rv_2 = __builtin_nontemporal_load((const unsigned int*)(resb + (size_t)n2 * D) + cp);
            int c2 = e1_2 - e0_2; if (c2 > 64) c2 = 64;
            mi_2 = (lane < c2) ? __builtin_nontemporal_load(csr_src + e0_2 + lane) : 0;
        }
        // ---- stage B: S1 first-32 prefetch (mi_1 ready since last iter) ----
        uint4 qv[4]; float qm[4];
        {
            int c1 = e1_1 - e0_1; if (c1 > 64) c1 = 64;
            prefetch32q(hwb8, mi_1, c1, qg, ql, qv, qm);
        }
        // ---- stage C: accumulate S0 ----
        int cnt0 = e1_0 - e0_0; if (cnt0 > 64) cnt0 = 64;
        f32x2 a8[8];
        #pragma unroll
        for (int i = 0; i < 8; i++) a8[i] = (f32x2)0.f;
        acc16m(a8, pv[0], pm[0]); acc16m(a8, pv[1], pm[1]);
        if (cnt0 > 16) {                       // wave-uniform
            acc16m(a8, pv[2], pm[2]); acc16m(a8, pv[3], pm[3]);
        }
        gather_rest(hwb8, mi_0, cnt0, qg, ql, a8);
        for (int j0 = e0_0 + 64; j0 < e1_0; j0 += 64) {
            int cnt = e1_0 - j0; if (cnt > 64) cnt = 64;
            int mw = (lane < cnt) ? __builtin_nontemporal_load(csr_src + j0 + lane) : 0;
            gather_accum(hwb8, mw, cnt, qg, ql, a8);
        }
        // ---- reduce-scatter over the 8 edge-slots (xor 8,16,32) ----
        #pragma unroll
        for (int b = 0; b < 3; b++) {
            int half = 4 >> b;
            int bit = (qg >> b) & 1;
            #pragma unroll
            for (int i = 0; i < half; i++) {
                f32x2 keep = bit ? a8[2 * i + 1] : a8[2 * i];
                f32x2 send = bit ? a8[2 * i]     : a8[2 * i + 1];
                f32x2 recv;
                recv.x = __shfl_xor(send.x, 8 << b);
                recv.y = __shfl_xor(send.y, 8 << b);
                a8[i] = keep + recv;
            }
        }
        // ---- epilogue: ALL 64 lanes, 2 channels each ----
        {
            float o0 = fmaxf(a8[0].x * ri_0 + bv.x, 0.f) + bf_lo(rv_0);
            float o1 = fmaxf(a8[0].y * ri_0 + bv.y, 0.f) + bf_hi(rv_0);
            ((unsigned int*)(yb + (size_t)n * D))[cp] = pack_rne(o0, o1);
            s1a += o0; s1b += o1; s2a += o0 * o0; s2b += o1 * o1;
        }
        // ---- rotate pipeline ----
        n += nw;
        e0_0 = e0_1; e1_0 = e1_1; mi_0 = mi_1; ri_0 = ri_1; rv_0 = rv_1;
        e0_1 = e0_2; e1_1 = e1_2; mi_1 = mi_2; ri_1 = ri_2; rv_1 = rv_2;
        #pragma unroll
        for (int i = 0; i < 4; i++) { pv[i] = qv[i]; pm[i] = qm[i]; }
    }
    // BN partial sums: lane owns channels 2cp, 2cp+1
    red[wid * 256 + 2 * cp]           = s1a;
    red[wid * 256 + 2 * cp + 1]       = s1b;
    red[wid * 256 + 128 + 2 * cp]     = s2a;
    red[wid * 256 + 128 + 2 * cp + 1] = s2b;
    __syncthreads();
    if (tid < 256) {
        float v = red[tid] + red[256 + tid] + red[512 + tid] + red[768 + tid];
        parts[(size_t)blockIdx.x * 256 + tid] = v;
    }
}

__global__ __launch_bounds__(256) void bn_fin2(
        const float* __restrict__ parts, const float* __restrict__ gamma,
        const float* __restrict__ beta, float* __restrict__ scsh) {
    __shared__ float rs1[256], rs2[256];
    int c = blockIdx.x, t = threadIdx.x;
    float s1 = 0.f, s2 = 0.f;
    for (int b = t; b < AGG_BLOCKS; b += 256) {
        s1 += parts[(size_t)b * 256 + c];
        s2 += parts[(size_t)b * 256 + 128 + c];
    }
    rs1[t] = s1; rs2[t] = s2;
    __syncthreads();
    for (int off = 128; off > 0; off >>= 1) {
        if (t < off) { rs1[t] += rs1[t + off]; rs2[t] += rs2[t + off]; }
        __syncthreads();
    }
    if (t == 0) {
        const float invN = 1.0f / (float)N_NODES;
        float mean = rs1[0] * invN;
        float var  = rs2[0] * invN - mean * mean;
        float sc = gamma[c] * rsqrtf(var + BN_EPS);
        scsh[c] = sc;
        scsh[128 + c] = beta[c] - mean * sc;
    }
}

__global__ void norm_kernel(const unsigned short* __restrict__ yb,
                            const float* __restrict__ scsh, float* __restrict__ out) {
    int i = blockIdx.x * blockDim.x + threadIdx.x;
    if (i < N_NODES * 16) {
        uint4 v = ((const uint4*)yb)[i];
        int c = (i & 15) * 8;
        f32x4 o0, o1;
        o0[0] = bf_lo(v.x) * scsh[c]     + scsh[128 + c];
        o0[1] = bf_hi(v.x) * scsh[c + 1] + scsh[128 + c + 1];
        o0[2] = bf_lo(v.y) * scsh[c + 2] + scsh[128 + c + 2];
        o0[3] = bf_hi(v.y) * scsh[c + 3] + scsh[128 + c + 3];
        o1[0] = bf_lo(v.z) * scsh[c + 4] + scsh[128 + c + 4];
        o1[1] = bf_hi(v.z) * scsh[c + 5] + scsh[128 + c + 5];
        o1[2] = bf_lo(v.w) * scsh[c + 6] + scsh[128 + c + 6];
        o1[3] = bf_hi(v.w) * scsh[c + 7] + scsh[128 + c + 7];
        f32x4* ov = (f32x4*)out + (size_t)i * 2;
        __builtin_nontemporal_store(o0, ov);
        __builtin_nontemporal_store(o1, ov + 1);
    }
}

extern "C" void kernel_launch(void* const* d_in, const int* in_sizes, int n_in,
                              void* d_out, int out_size, void* d_ws, size_t ws_size,
                              hipStream_t stream) {
    const float* x     = (const float*)d_in[0];
    const int*   src   = (const int*)d_in[1];
    const int*   dst   = (const int*)d_in[2];
    const float* W     = (const float*)d_in[3];
    const float* b     = (const float*)d_in[4];
    const float* Wr    = (const float*)d_in[5];
    const float* br    = (const float*)d_in[6];
    const float* gamma = (const float*)d_in[7];
    const float* beta  = (const float*)d_in[8];
    float* out = (float*)d_out;

    char* ws = (char*)d_ws;
    int*   cnt_in  = (int*)(ws + 0);
    int*   cnt_out = (int*)(ws + 262144);
    int*   row_ptr = (int*)(ws + 524288);
    float* scsh    = (float*)(ws + 1310720);
    int*   blk_sum = (int*)(ws + 1312768);
    int*   csr_src = (int*)(ws + 1576960);
    unsigned char*  hwb8 = (unsigned char*)(ws + 4800000);
    unsigned short* resb = (unsigned short*)(ws + 11200000);
    unsigned short* yb   = (unsigned short*)(ws + 24000000);
    float* parts   = (float*)(ws + 36800000);
    uint4* pW      = (uint4*)(ws + 38897152);
    uint4* pWr     = (uint4*)(ws + 38929920);
    unsigned int* histD = (unsigned int*)(ws + 38962688);
    unsigned int* histS = (unsigned int*)(ws + 45516288);

    hist_kernel<<<dim3(CHUNKS + 16, 4, 2), 256, 0, stream>>>(
        dst, src, histD, histS, W, Wr, pW, pWr);
    merge_kernel<<<dim3(NB_MERGE, 2), 256, 0, stream>>>(
        histD, histS, (int*)cnt_in, (int*)cnt_out, row_ptr, blk_sum);
    fill2_kernel<<<dim3(CHUNKS, 4), 512, 0, stream>>>(
        src, dst, row_ptr, histD, blk_sum, csr_src);
    gemm_mfma<<<(N_NODES + 63) / 64, 256, 0, stream>>>(
        x, pW, pWr, br, (const unsigned int*)cnt_out, hwb8, resb);
    agg_kernel<<<AGG_BLOCKS, 256, 0, stream>>>(
        hwb8, row_ptr, blk_sum, (const unsigned int*)cnt_in, csr_src, b, resb, yb, parts);
    bn_fin2<<<128, 256, 0, stream>>>(parts, gamma, beta, scsh);
    norm_kernel<<<(N_NODES * 16 + 255) / 256, 256, 0, stream>>>(yb, scsh, out);
}

// Round 14
// 203.749 us; speedup vs baseline: 1.0417x; 1.0208x over previous
//
#include <hip/hip_runtime.h>

#define N_NODES 50000
#define N_EDGES 800000
#define D 128
#define BN_EPS 1e-5f
#define AGG_BLOCKS 2048
#define CHUNKS 64
#define EPC (N_EDGES / CHUNKS)    // 12500 edges per chunk (u16-safe ranks)
#define EPC4 (EPC / 4)            // 3125 int4 loads (chunk base 16B-aligned)
#define QUART_BINS 12800          // node-range quarter
#define QUART_U32 6400            // u32 words per quarter (2 bins/word)
#define NB_MERGE 100              // merge blocks: 512 consecutive nodes each
#define NB_PER_Q 25               // merge blocks per quarter (25*256 = 6400 words)

typedef short bf16x8 __attribute__((ext_vector_type(8)));
typedef float f32x4  __attribute__((ext_vector_type(4)));
typedef float f32x2  __attribute__((ext_vector_type(2)));
typedef unsigned int u32x4 __attribute__((ext_vector_type(4)));
typedef int i32x4 __attribute__((ext_vector_type(4)));   // native vec: nontemporal-safe

// ---------------- workspace layout (bytes) ----------------
// cnt_in @0 (256KB)  cnt_out @262144 (256KB)  row_ptr @524288 (local prefix)
// scsh @1310720  blk_sum @1312768 (100 ints)  csr_src @1576960 (3.2MB)
// hwb8(fp8 [row][col]) @4800000 (6.4MB)  resb(bf16) @11200000 (12.8MB)
// yb @24000000 (12.8MB)  parts @36800000 (2.1MB)
// pW @38897152  pWr @38929920  histD @38962688 (6.55MB)  histS @45516288 (6.55MB)
// hist layout: [(quarter*CHUNKS + chunk)][QUART_U32]

__device__ __forceinline__ unsigned int pack_rne(float a, float b) {
    unsigned int ua = __float_as_uint(a); ua += 0x7fffu + ((ua >> 16) & 1u);
    unsigned int ub = __float_as_uint(b); ub += 0x7fffu + ((ub >> 16) & 1u);
    return (ua >> 16) | (ub & 0xffff0000u);
}
__device__ __forceinline__ unsigned short pack1_rne(float a) {
    unsigned int ua = __float_as_uint(a); ua += 0x7fffu + ((ua >> 16) & 1u);
    return (unsigned short)(ua >> 16);
}
__device__ __forceinline__ unsigned char pack1_fp8(float a) {
    unsigned int u = __builtin_amdgcn_cvt_pk_fp8_f32(a, a, 0, false);
    return (unsigned char)(u & 0xffu);
}

// Shared: per-block LDS scan of the NB_MERGE block totals. sh[] = INCLUSIVE sums.
__device__ __forceinline__ void scan_blksum(const int* __restrict__ blk_sum,
                                            int* sh, int t) {
    int v = (t < NB_MERGE) ? blk_sum[t] : 0;
    if (t < 256) sh[t] = v;
    __syncthreads();
    int inc = v;
    #pragma unroll
    for (int off = 1; off < 256; off <<= 1) {
        int u = (t >= off && t < 256) ? sh[t - off] : 0;
        __syncthreads();
        inc += u;
        if (t < 256) sh[t] = inc;
        __syncthreads();
    }
}
#define BLK_OFF(sh, mb) ((mb) ? (sh)[(mb) - 1] : 0)

// Privatized LDS histogram, grid (chunk[+pack], r-QUARTER, key) = 512 working
// blocks (2/CU), 25.6KB LDS each. int4 edge loads.
// Blocks x >= CHUNKS (y==0,z==0) do the W/Wr pre-pack.
__global__ __launch_bounds__(256) void hist_kernel(
        const int* __restrict__ dst, const int* __restrict__ src,
        unsigned int* __restrict__ histD, unsigned int* __restrict__ histS,
        const float* __restrict__ W, const float* __restrict__ Wr,
        uint4* __restrict__ pW, uint4* __restrict__ pWr) {
    __shared__ unsigned int h[QUART_U32];
    int tid = threadIdx.x;
    int c = blockIdx.x, r = blockIdx.y;
    if (c >= CHUNKS) {
        if (r != 0 || blockIdx.z != 0) return;
        int t = (c - CHUNKS) * 256 + tid;
        const float* S = (t & 2048) ? Wr : W;
        uint4* Dst     = (t & 2048) ? pWr : pW;
        int e = t & 2047;
        int lane = e & 63, ks = (e >> 6) & 3, ct = e >> 8;
        int n  = ct * 16 + (lane & 15);
        int k0 = ks * 32 + (lane >> 4) * 8;
        float v[8];
        #pragma unroll
        for (int j = 0; j < 8; j++) v[j] = S[(k0 + j) * D + n];
        uint4 rr;
        rr.x = pack_rne(v[0], v[1]); rr.y = pack_rne(v[2], v[3]);
        rr.z = pack_rne(v[4], v[5]); rr.w = pack_rne(v[6], v[7]);
        Dst[e] = rr;
        return;
    }
    const int* keys = blockIdx.z ? src : dst;
    unsigned int* hist = blockIdx.z ? histS : histD;
    for (int j = tid; j < QUART_U32; j += 256) h[j] = 0u;
    __syncthreads();
    int lo = r * QUART_BINS;
    const i32x4* keys4 = (const i32x4*)(keys + c * EPC);   // 16B-aligned
    for (int i = tid; i < EPC4; i += 256) {
        i32x4 k = __builtin_nontemporal_load(keys4 + i);
        int b0 = k.x - lo, b1 = k.y - lo, b2 = k.z - lo, b3 = k.w - lo;
        if ((unsigned)b0 < (unsigned)QUART_BINS) atomicAdd(&h[b0 >> 1], 1u << ((b0 & 1) * 16));
        if ((unsigned)b1 < (unsigned)QUART_BINS) atomicAdd(&h[b1 >> 1], 1u << ((b1 & 1) * 16));
        if ((unsigned)b2 < (unsigned)QUART_BINS) atomicAdd(&h[b2 >> 1], 1u << ((b2 & 1) * 16));
        if ((unsigned)b3 < (unsigned)QUART_BINS) atomicAdd(&h[b3 >> 1], 1u << ((b3 & 1) * 16));
    }
    __syncthreads();
    unsigned int* out = hist + ((size_t)(r * CHUNKS + c)) * QUART_U32;
    for (int j = tid; j < QUART_U32; j += 256) out[j] = h[j];
}

// merge, grid (100, key): each block = 256 words = 512 consecutive nodes.
__global__ __launch_bounds__(256) void merge_kernel(
        unsigned int* __restrict__ histD, unsigned int* __restrict__ histS,
        int* __restrict__ cnt_in, int* __restrict__ cnt_out,
        int* __restrict__ row_ptr, int* __restrict__ blk_sum) {
    __shared__ int sh[256];
    int t = threadIdx.x;
    int bx = blockIdx.x;
    int r = bx / NB_PER_Q;
    int q = (bx % NB_PER_Q) * 256 + t;         // word index within quarter
    int n0 = bx * 512 + t * 2;                 // consecutive node id
    if (blockIdx.y) {
        size_t base = (size_t)r * CHUNKS * QUART_U32 + q;
        unsigned int vals[CHUNKS];
        #pragma unroll
        for (int c = 0; c < CHUNKS; c++)
            vals[c] = histS[base + (size_t)c * QUART_U32];   // independent loads
        unsigned int lo = 0, hi = 0;
        #pragma unroll
        for (int c = 0; c < CHUNKS; c++) {
            lo += vals[c] & 0xffffu; hi += vals[c] >> 16;
        }
        cnt_out[n0]     = (int)lo;
        cnt_out[n0 + 1] = (int)hi;
        return;                                // no barriers taken
    }
    size_t base = (size_t)r * CHUNKS * QUART_U32 + q;
    unsigned int vals[CHUNKS];
    #pragma unroll
    for (int c = 0; c < CHUNKS; c++)
        vals[c] = histD[base + (size_t)c * QUART_U32];   // independent loads
    unsigned int lo = 0, hi = 0;
    #pragma unroll
    for (int c = 0; c < CHUNKS; c++) {
        unsigned int v = vals[c];
        histD[base + (size_t)c * QUART_U32] = lo | (hi << 16);  // exclusive prefix
        lo += v & 0xffffu; hi += v >> 16;
    }
    cnt_in[n0]     = (int)lo;
    cnt_in[n0 + 1] = (int)hi;
    // fused intra-block scan over this block's 512 node counts
    int pair = (int)lo + (int)hi;
    sh[t] = pair;
    __syncthreads();
    int inc = pair;
    #pragma unroll
    for (int off = 1; off < 256; off <<= 1) {
        int u = (t >= off) ? sh[t - off] : 0;
        __syncthreads();
        inc += u; sh[t] = inc;
        __syncthreads();
    }
    int excl = inc - pair;
    row_ptr[n0]     = excl;                    // LOCAL prefix (block-relative)
    row_ptr[n0 + 1] = excl + (int)lo;
    if (t == 255) blk_sum[bx] = inc;           // block TOTAL (nodes bx*512..+511)
}

// Counting-sort CSR fill, grid (chunk, bin-QUARTER) = 256 blocks.
__global__ __launch_bounds__(512) void fill2_kernel(
        const int* __restrict__ src, const int* __restrict__ dst,
        const int* __restrict__ row_ptr, const unsigned int* __restrict__ histP,
        const int* __restrict__ blk_sum, int* __restrict__ csr_src) {
    __shared__ unsigned int h[QUART_U32];
    __shared__ int sho[256];
    int tid = threadIdx.x;
    scan_blksum(blk_sum, sho, tid);
    int c = blockIdx.x, s = blockIdx.y;        // quarter 0..3
    int base = c * EPC;
    for (int j = tid; j < QUART_U32; j += 512) h[j] = 0u;
    __syncthreads();
    int lo = s * QUART_BINS;
    const unsigned int* pre_c = histP + ((size_t)(s * CHUNKS + c)) * QUART_U32;
    for (int i = tid; i < EPC; i += 512) {
        int d = __builtin_nontemporal_load(dst + base + i);
        int b = d - lo;
        if ((unsigned)b < (unsigned)QUART_BINS) {
            int shft = (b & 1) * 16;
            unsigned int old = atomicAdd(&h[b >> 1], 1u << shft);
            unsigned int rank = (old >> shft) & 0xffffu;
            unsigned int pre = (pre_c[b >> 1] >> shft) & 0xffffu;
            int p = row_ptr[d] + BLK_OFF(sho, d >> 9) + (int)(pre + rank);
            csr_src[p] = __builtin_nontemporal_load(src + base + i);
        }
    }
}

// MFMA dual GEMM, coalesced A-staging through LDS (bf16).
// hwb8 = fp8e4m3(rout*(x@W)) [row][col] (128B rows); resb = bf16(relu(x@Wr+br)).
__global__ __launch_bounds__(256) void gemm_mfma(
        const float* __restrict__ x, const uint4* __restrict__ pW,
        const uint4* __restrict__ pWr, const float* __restrict__ br,
        const unsigned int* __restrict__ cnt_out, unsigned char* __restrict__ hwb8,
        unsigned short* __restrict__ resb) {
    __shared__ unsigned short xs[64][136];
    int tid = threadIdx.x, wid = tid >> 6, lane = tid & 63;
    int quad = lane >> 4, l15 = lane & 15;
    int r0b = blockIdx.x * 64;
    const float4* xg = (const float4*)(x + (size_t)r0b * D);
    int maxidx = (N_NODES - r0b) * (D / 4);
    #pragma unroll
    for (int i = 0; i < 8; i++) {
        int idx = tid + 256 * i;
        float4 v = (idx < maxidx) ? xg[idx] : make_float4(0.f, 0.f, 0.f, 0.f);
        int row = idx >> 5, c0 = (idx & 31) * 4;
        *(unsigned int*)&xs[row][c0]     = pack_rne(v.x, v.y);
        *(unsigned int*)&xs[row][c0 + 2] = pack_rne(v.z, v.w);
    }
    __syncthreads();
    int wrow0 = wid * 16;
    bf16x8 A[4];
    #pragma unroll
    for (int ks = 0; ks < 4; ks++)
        A[ks] = *(const bf16x8*)&xs[wrow0 + l15][ks * 32 + quad * 8];
    f32x4 accW[8], accR[8];
    #pragma unroll
    for (int ct = 0; ct < 8; ct++) { accW[ct] = (f32x4)0.f; accR[ct] = (f32x4)0.f; }
    #pragma unroll
    for (int ct = 0; ct < 8; ct++) {
        #pragma unroll
        for (int ks = 0; ks < 4; ks++) {
            union { bf16x8 v; uint4 u; } Bw, Br2;
            Bw.u  = pW [(ct * 4 + ks) * 64 + lane];
            Br2.u = pWr[(ct * 4 + ks) * 64 + lane];
            accW[ct] = __builtin_amdgcn_mfma_f32_16x16x32_bf16(A[ks], Bw.v,  accW[ct], 0, 0, 0);
            accR[ct] = __builtin_amdgcn_mfma_f32_16x16x32_bf16(A[ks], Br2.v, accR[ct], 0, 0, 0);
        }
    }
    int r0 = r0b + wrow0;
    float ro[4]; int rowok[4];
    #pragma unroll
    for (int reg = 0; reg < 4; reg++) {
        int row = r0 + quad * 4 + reg;
        rowok[reg] = row < N_NODES;
        int cw = (int)cnt_out[rowok[reg] ? row : N_NODES - 1];
        ro[reg] = rsqrtf((float)(cw > 1 ? cw : 1));
    }
    #pragma unroll
    for (int ct = 0; ct < 8; ct++) {
        int c = ct * 16 + l15;
        float brv = br[c];
        #pragma unroll
        for (int reg = 0; reg < 4; reg++) {
            int row = r0 + quad * 4 + reg;
            if (rowok[reg]) {
                hwb8[(size_t)row * D + c] = pack1_fp8(accW[ct][reg] * ro[reg]);
                resb[(size_t)row * D + c] = pack1_rne(fmaxf(accR[ct][reg] + brv, 0.f));
            }
        }
    }
}

__device__ __forceinline__ float bf_lo(unsigned int v) { return __uint_as_float(v << 16); }
__device__ __forceinline__ float bf_hi(unsigned int v) { return __uint_as_float(v & 0xffff0000u); }

// 16-value fp8 accumulate from one uint4 (8 cvt + 8 pk-add)
__device__ __forceinline__ void acc16(f32x2* a, const uint4 v) {
    a[0] += __builtin_amdgcn_cvt_pk_f32_fp8(v.x, false);
    a[1] += __builtin_amdgcn_cvt_pk_f32_fp8(v.x, true);
    a[2] += __builtin_amdgcn_cvt_pk_f32_fp8(v.y, false);
    a[3] += __builtin_amdgcn_cvt_pk_f32_fp8(v.y, true);
    a[4] += __builtin_amdgcn_cvt_pk_f32_fp8(v.z, false);
    a[5] += __builtin_amdgcn_cvt_pk_f32_fp8(v.z, true);
    a[6] += __builtin_amdgcn_cvt_pk_f32_fp8(v.w, false);
    a[7] += __builtin_amdgcn_cvt_pk_f32_fp8(v.w, true);
}
__device__ __forceinline__ void acc16m(f32x2* a, const uint4 v, float m) {
    f32x2 m2 = {m, m};
    a[0] += m2 * __builtin_amdgcn_cvt_pk_f32_fp8(v.x, false);
    a[1] += m2 * __builtin_amdgcn_cvt_pk_f32_fp8(v.x, true);
    a[2] += m2 * __builtin_amdgcn_cvt_pk_f32_fp8(v.y, false);
    a[3] += m2 * __builtin_amdgcn_cvt_pk_f32_fp8(v.y, true);
    a[4] += m2 * __builtin_amdgcn_cvt_pk_f32_fp8(v.z, false);
    a[5] += m2 * __builtin_amdgcn_cvt_pk_f32_fp8(v.z, true);
    a[6] += m2 * __builtin_amdgcn_cvt_pk_f32_fp8(v.w, false);
    a[7] += m2 * __builtin_amdgcn_cvt_pk_f32_fp8(v.w, true);
}

// Issue the FIRST-16-edge gathers (2 independent uint4 loads, 8 lanes/edge)
// with clamp+mask. Loads stay in flight a full pipeline iteration.
__device__ __forceinline__ void prefetch16q(
        const unsigned char* __restrict__ hwb8, int myidx, int cnt,
        int qg, int ql, uint4& v0, uint4& v1, float& m0, float& m1) {
    int cm = cnt - 1; if (cm < 0) cm = 0;
    int j0 = qg, j1 = 8 + qg;
    m0 = (j0 < cnt) ? 1.f : 0.f;
    m1 = (j1 < cnt) ? 1.f : 0.f;
    if (j0 > cm) j0 = cm;
    if (j1 > cm) j1 = cm;
    int p0 = __shfl(myidx, j0);
    int p1 = __shfl(myidx, j1);
    v0 = *((const uint4*)(hwb8 + (size_t)p0 * 128) + ql);
    v1 = *((const uint4*)(hwb8 + (size_t)p1 * 128) + ql);
}

// Synchronous gather of edges [16, cnt) of a window (prefetch covered 0..15).
__device__ __forceinline__ void gather_rest(
        const unsigned char* __restrict__ hwb8, int myidx, int cnt,
        int qg, int ql, f32x2* a) {
    int i = 16;
    for (; i + 8 <= cnt; i += 8) {
        int p0 = __shfl(myidx, i + qg);
        uint4 v0 = *((const uint4*)(hwb8 + (size_t)p0 * 128) + ql);
        acc16(a, v0);
    }
    int t = cnt - i;
    if (t > 0) {
        int j = i + qg; if (j > cnt - 1) j = cnt - 1;
        int p0 = __shfl(myidx, j);
        uint4 v0 = *((const uint4*)(hwb8 + (size_t)p0 * 128) + ql);
        float m = (qg < t) ? 1.f : 0.f;
        acc16m(a, v0, m);
    }
}

// Full synchronous window gather (extra windows beyond the first 64 edges).
__device__ __forceinline__ void gather_accum(
        const unsigned char* __restrict__ hwb8, int myidx, int cnt,
        int qg, int ql, f32x2* a) {
    int i = 0;
    for (; i + 8 <= cnt; i += 8) {
        int p0 = __shfl(myidx, i + qg);
        uint4 v0 = *((const uint4*)(hwb8 + (size_t)p0 * 128) + ql);
        acc16(a, v0);
    }
    int t = cnt - i;
    if (t > 0) {
        int j = i + qg; if (j > cnt - 1) j = cnt - 1;
        int p0 = __shfl(myidx, j);
        uint4 v0 = *((const uint4*)(hwb8 + (size_t)p0 * 128) + ql);
        float m = (qg < t) ? 1.f : 0.f;
        acc16m(a, v0, m);
    }
}

// Per-dst aggregation, 8-lanes/edge uint4 gathers (half the load-issues and
// shfls of the 16-lane/uint2 form), 3-stage pipeline, reduce-SCATTER over the
// 8 edge-slots (14 shfl + 7 pk-add), epilogue spread over ALL 64 lanes
// (each lane owns channel pair cp = ql*8+qg). No global atomics.
__global__ __launch_bounds__(256) void agg_kernel(
        const unsigned char* __restrict__ hwb8, const int* __restrict__ row_ptr,
        const int* __restrict__ blk_sum, const unsigned int* __restrict__ cnt_in,
        const int* __restrict__ csr_src,
        const float* __restrict__ bias, const unsigned short* __restrict__ resb,
        unsigned short* __restrict__ yb, float* __restrict__ parts) {
    __shared__ float red[4 * 256];
    __shared__ int sho[256];
    int tid = threadIdx.x;
    scan_blksum(blk_sum, sho, tid);
    int lane = tid & 63, wid = tid >> 6;
    int wave = blockIdx.x * 4 + wid;
    int nw = AGG_BLOCKS * 4;
    int qg = lane >> 3;                 // edge slot (0..7)
    int ql = lane & 7;                  // 16B segment of the 128B row
    int cp = ql * 8 + qg;               // channel-pair this lane owns post-reduce
    float2 bv = ((const float2*)bias)[cp];
    float s1a = 0.f, s1b = 0.f, s2a = 0.f, s2b = 0.f;

    // pipeline state
    int e0_0 = 0, e1_0 = 0, mi_0 = 0; float ri_0 = 0.f; unsigned int rv_0 = 0u;
    int e0_1 = 0, e1_1 = 0, mi_1 = 0; float ri_1 = 0.f; unsigned int rv_1 = 0u;
    uint4 pv0, pv1; float pm0 = 0.f, pm1 = 0.f;
    pv0 = pv1 = make_uint4(0u, 0u, 0u, 0u);

    int n = wave;
    if (n < N_NODES) {                                 // prologue: S0 state
        e0_0 = row_ptr[n] + BLK_OFF(sho, n >> 9);
        e1_0 = row_ptr[n + 1] + BLK_OFF(sho, (n + 1) >> 9);
        int ci = (int)cnt_in[n];
        ri_0 = rsqrtf((float)(ci > 1 ? ci : 1));
        rv_0 = __builtin_nontemporal_load((const unsigned int*)(resb + (size_t)n * D) + cp);
        int c0 = e1_0 - e0_0; if (c0 > 64) c0 = 64;
        mi_0 = (lane < c0) ? __builtin_nontemporal_load(csr_src + e0_0 + lane) : 0;
        prefetch16q(hwb8, mi_0, c0, qg, ql, pv0, pv1, pm0, pm1);
    }
    int n1g = n + nw;
    if (n1g < N_NODES) {                               // prologue: S1 state
        e0_1 = row_ptr[n1g] + BLK_OFF(sho, n1g >> 9);
        e1_1 = row_ptr[n1g + 1] + BLK_OFF(sho, (n1g + 1) >> 9);
        int ci = (int)cnt_in[n1g];
        ri_1 = rsqrtf((float)(ci > 1 ? ci : 1));
        rv_1 = __builtin_nontemporal_load((const unsigned int*)(resb + (size_t)n1g * D) + cp);
        int c1 = e1_1 - e0_1; if (c1 > 64) c1 = 64;
        mi_1 = (lane < c1) ? __builtin_nontemporal_load(csr_src + e0_1 + lane) : 0;
    }

    while (n < N_NODES) {
        int n2 = n + 2 * nw;
        // ---- stage A: S2 index/meta loads ----
        int e0_2 = 0, e1_2 = 0, mi_2 = 0; float ri_2 = 0.f; unsigned int rv_2 = 0u;
        if (n2 < N_NODES) {
            e0_2 = row_ptr[n2] + BLK_OFF(sho, n2 >> 9);
            e1_2 = row_ptr[n2 + 1] + BLK_OFF(sho, (n2 + 1) >> 9);
            int ci = (int)cnt_in[n2];
            ri_2 = rsqrtf((float)(ci > 1 ? ci : 1));
            rv_2 = __builtin_nontemporal_load((const unsigned int*)(resb + (size_t)n2 * D) + cp);
            int c2 = e1_2 - e0_2; if (c2 > 64) c2 = 64;
            mi_2 = (lane < c2) ? __builtin_nontemporal_load(csr_src + e0_2 + lane) : 0;
        }
        // ---- stage B: S1 first-16 prefetch (mi_1 ready since last iter) ----
        uint4 qv0, qv1; float qm0, qm1;
        {
            int c1 = e1_1 - e0_1; if (c1 > 64) c1 = 64;
            prefetch16q(hwb8, mi_1, c1, qg, ql, qv0, qv1, qm0, qm1);
        }
        // ---- stage C: accumulate S0 ----
        f32x2 a8[8];
        #pragma unroll
        for (int i = 0; i < 8; i++) a8[i] = (f32x2)0.f;
        acc16m(a8, pv0, pm0); acc16m(a8, pv1, pm1);
        {
            int cnt = e1_0 - e0_0; if (cnt > 64) cnt = 64;
            gather_rest(hwb8, mi_0, cnt, qg, ql, a8);
        }
        for (int j0 = e0_0 + 64; j0 < e1_0; j0 += 64) {
            int cnt = e1_0 - j0; if (cnt > 64) cnt = 64;
            int mw = (lane < cnt) ? __builtin_nontemporal_load(csr_src + j0 + lane) : 0;
            gather_accum(hwb8, mw, cnt, qg, ql, a8);
        }
        // ---- reduce-scatter over the 8 edge-slots (xor 8,16,32) ----
        #pragma unroll
        for (int b = 0; b < 3; b++) {
            int half = 4 >> b;
            int bit = (qg >> b) & 1;
            #pragma unroll
            for (int i = 0; i < half; i++) {
                f32x2 keep = bit ? a8[2 * i + 1] : a8[2 * i];
                f32x2 send = bit ? a8[2 * i]     : a8[2 * i + 1];
                f32x2 recv;
                recv.x = __shfl_xor(send.x, 8 << b);
                recv.y = __shfl_xor(send.y, 8 << b);
                a8[i] = keep + recv;
            }
        }
        // ---- epilogue: ALL 64 lanes, 2 channels each ----
        {
            float o0 = fmaxf(a8[0].x * ri_0 + bv.x, 0.f) + bf_lo(rv_0);
            float o1 = fmaxf(a8[0].y * ri_0 + bv.y, 0.f) + bf_hi(rv_0);
            ((unsigned int*)(yb + (size_t)n * D))[cp] = pack_rne(o0, o1);
            s1a += o0; s1b += o1; s2a += o0 * o0; s2b += o1 * o1;
        }
        // ---- rotate pipeline ----
        n += nw;
        e0_0 = e0_1; e1_0 = e1_1; mi_0 = mi_1; ri_0 = ri_1; rv_0 = rv_1;
        e0_1 = e0_2; e1_1 = e1_2; mi_1 = mi_2; ri_1 = ri_2; rv_1 = rv_2;
        pv0 = qv0; pv1 = qv1; pm0 = qm0; pm1 = qm1;
    }
    // BN partial sums: lane owns channels 2cp, 2cp+1
    red[wid * 256 + 2 * cp]           = s1a;
    red[wid * 256 + 2 * cp + 1]       = s1b;
    red[wid * 256 + 128 + 2 * cp]     = s2a;
    red[wid * 256 + 128 + 2 * cp + 1] = s2b;
    __syncthreads();
    if (tid < 256) {
        float v = red[tid] + red[256 + tid] + red[512 + tid] + red[768 + tid];
        parts[(size_t)blockIdx.x * 256 + tid] = v;
    }
}

__global__ __launch_bounds__(256) void bn_fin2(
        const float* __restrict__ parts, const float* __restrict__ gamma,
        const float* __restrict__ beta, float* __restrict__ scsh) {
    __shared__ float rs1[256], rs2[256];
    int c = blockIdx.x, t = threadIdx.x;
    float s1 = 0.f, s2 = 0.f;
    for (int b = t; b < AGG_BLOCKS; b += 256) {
        s1 += parts[(size_t)b * 256 + c];
        s2 += parts[(size_t)b * 256 + 128 + c];
    }
    rs1[t] = s1; rs2[t] = s2;
    __syncthreads();
    for (int off = 128; off > 0; off >>= 1) {
        if (t < off) { rs1[t] += rs1[t + off]; rs2[t] += rs2[t + off]; }
        __syncthreads();
    }
    if (t == 0) {
        const float invN = 1.0f / (float)N_NODES;
        float mean = rs1[0] * invN;
        float var  = rs2[0] * invN - mean * mean;
        float sc = gamma[c] * rsqrtf(var + BN_EPS);
        scsh[c] = sc;
        scsh[128 + c] = beta[c] - mean * sc;
    }
}

__global__ void norm_kernel(const unsigned short* __restrict__ yb,
                            const float* __restrict__ scsh, float* __restrict__ out) {
    int i = blockIdx.x * blockDim.x + threadIdx.x;
    if (i < N_NODES * 16) {
        uint4 v = ((const uint4*)yb)[i];
        int c = (i & 15) * 8;
        f32x4 o0, o1;
        o0[0] = bf_lo(v.x) * scsh[c]     + scsh[128 + c];
        o0[1] = bf_hi(v.x) * scsh[c + 1] + scsh[128 + c + 1];
        o0[2] = bf_lo(v.y) * scsh[c + 2] + scsh[128 + c + 2];
        o0[3] = bf_hi(v.y) * scsh[c + 3] + scsh[128 + c + 3];
        o1[0] = bf_lo(v.z) * scsh[c + 4] + scsh[128 + c + 4];
        o1[1] = bf_hi(v.z) * scsh[c + 5] + scsh[128 + c + 5];
        o1[2] = bf_lo(v.w) * scsh[c + 6] + scsh[128 + c + 6];
        o1[3] = bf_hi(v.w) * scsh[c + 7] + scsh[128 + c + 7];
        f32x4* ov = (f32x4*)out + (size_t)i * 2;
        __builtin_nontemporal_store(o0, ov);
        __builtin_nontemporal_store(o1, ov + 1);
    }
}

extern "C" void kernel_launch(void* const* d_in, const int* in_sizes, int n_in,
                              void* d_out, int out_size, void* d_ws, size_t ws_size,
                              hipStream_t stream) {
    const float* x     = (const float*)d_in[0];
    const int*   src   = (const int*)d_in[1];
    const int*   dst   = (const int*)d_in[2];
    const float* W     = (const float*)d_in[3];
    const float* b     = (const float*)d_in[4];
    const float* Wr    = (const float*)d_in[5];
    const float* br    = (const float*)d_in[6];
    const float* gamma = (const float*)d_in[7];
    const float* beta  = (const float*)d_in[8];
    float* out = (float*)d_out;

    char* ws = (char*)d_ws;
    int*   cnt_in  = (int*)(ws + 0);
    int*   cnt_out = (int*)(ws + 262144);
    int*   row_ptr = (int*)(ws + 524288);
    float* scsh    = (float*)(ws + 1310720);
    int*   blk_sum = (int*)(ws + 1312768);
    int*   csr_src = (int*)(ws + 1576960);
    unsigned char*  hwb8 = (unsigned char*)(ws + 4800000);
    unsigned short* resb = (unsigned short*)(ws + 11200000);
    unsigned short* yb   = (unsigned short*)(ws + 24000000);
    float* parts   = (float*)(ws + 36800000);
    uint4* pW      = (uint4*)(ws + 38897152);
    uint4* pWr     = (uint4*)(ws + 38929920);
    unsigned int* histD = (unsigned int*)(ws + 38962688);
    unsigned int* histS = (unsigned int*)(ws + 45516288);

    hist_kernel<<<dim3(CHUNKS + 16, 4, 2), 256, 0, stream>>>(
        dst, src, histD, histS, W, Wr, pW, pWr);
    merge_kernel<<<dim3(NB_MERGE, 2), 256, 0, stream>>>(
        histD, histS, (int*)cnt_in, (int*)cnt_out, row_ptr, blk_sum);
    fill2_kernel<<<dim3(CHUNKS, 4), 512, 0, stream>>>(
        src, dst, row_ptr, histD, blk_sum, csr_src);
    gemm_mfma<<<(N_NODES + 63) / 64, 256, 0, stream>>>(
        x, pW, pWr, br, (const unsigned int*)cnt_out, hwb8, resb);
    agg_kernel<<<AGG_BLOCKS, 256, 0, stream>>>(
        hwb8, row_ptr, blk_sum, (const unsigned int*)cnt_in, csr_src, b, resb, yb, parts);
    bn_fin2<<<128, 256, 0, stream>>>(parts, gamma, beta, scsh);
    norm_kernel<<<(N_NODES * 16 + 255) / 256, 256, 0, stream>>>(yb, scsh, out);
}